// Round 7
// baseline (321.853 us; speedup 1.0000x reference)
//
#include <hip/hip_runtime.h>
#include <hip/hip_bf16.h>

// CausalSelfAttention: x[4,2048,1024] -> qkv proj -> 16-head causal attn -> out proj
// Pipeline: cvt(fp32->bf16) x3 -> gemm_bt<QKV> -> attn (block-coop staged,
// counted-vmcnt pipeline) -> gemm_bt<OUT>

#define B_ 4
#define T_ 2048
#define C_ 1024
#define H_ 16
#define D_ 64
#define M_ (B_*T_)   // 8192 tokens

typedef __attribute__((ext_vector_type(8))) short short8;
typedef __attribute__((ext_vector_type(4))) float f32x4;

static __device__ __forceinline__ ushort f2bf(float f) {
  __hip_bfloat16 b = __float2bfloat16(f);
  ushort u; __builtin_memcpy(&u, &b, 2); return u;
}

static __device__ __forceinline__ void ld16(const void* g, void* l) {
  __builtin_amdgcn_global_load_lds((const __attribute__((address_space(1))) void*)g,
                                   (__attribute__((address_space(3))) void*)l, 16, 0, 0);
}

static __device__ __forceinline__ f32x4 mfma16(short8 a, short8 b, f32x4 c) {
  return __builtin_amdgcn_mfma_f32_16x16x32_bf16(a, b, c, 0, 0, 0);
}

// ---------------- fp32 -> bf16 convert ----------------
__global__ void cvt_bf16(const float* __restrict__ in, ushort* __restrict__ out, int n4) {
  int i = blockIdx.x * blockDim.x + threadIdx.x;
  int st = gridDim.x * blockDim.x;
  for (; i < n4; i += st) {
    float4 v = ((const float4*)in)[i];
    ushort4 o;
    o.x = f2bf(v.x); o.y = f2bf(v.y); o.z = f2bf(v.z); o.w = f2bf(v.w);
    ((ushort4*)out)[i] = o;
  }
}

// ---------------- C = A @ B^T + bias (both A,B K-major bf16) ----------------
// MODE 0: QKV projection -> scatter to q[B,H,T,D], k[B,H,T,D], vt[B,H,D,T] (bf16)
// MODE 1: out projection -> fp32 d_out
template<int MODE>
__global__ __launch_bounds__(256) void gemm_bt(
    const ushort* __restrict__ A, const ushort* __restrict__ Bm,
    const float* __restrict__ bias, int K,
    ushort* __restrict__ q, ushort* __restrict__ kk, ushort* __restrict__ vt,
    float* __restrict__ outF)
{
  __shared__ ushort Al[128*32];
  __shared__ ushort Bl[128*32];
  const int tid = threadIdx.x;
  const int lane = tid & 63;
  const int w = tid >> 6;
  const int wr = w >> 1, wc = w & 1;
  const int l15 = lane & 15, lhi = lane >> 4;
  const long i0 = (long)blockIdx.y * 128;
  const long j0 = (long)blockIdx.x * 128;

  f32x4 acc[4][4] = {};

  for (int k0 = 0; k0 < K; k0 += 32) {
    __syncthreads();
    {
      int c = tid;
      ld16((const char*)A  + ((i0 + (c >> 2)) * K + k0 + (c & 3) * 8) * 2, (char*)Al + c * 16);
      ld16((const char*)Bm + ((j0 + (c >> 2)) * K + k0 + (c & 3) * 8) * 2, (char*)Bl + c * 16);
      c = tid + 256;
      ld16((const char*)A  + ((i0 + (c >> 2)) * K + k0 + (c & 3) * 8) * 2, (char*)Al + c * 16);
      ld16((const char*)Bm + ((j0 + (c >> 2)) * K + k0 + (c & 3) * 8) * 2, (char*)Bl + c * 16);
    }
    __syncthreads();
    short8 af[4], bf[4];
#pragma unroll
    for (int m = 0; m < 4; m++) af[m] = *(const short8*)&Al[(wr*64 + m*16 + l15)*32 + lhi*8];
#pragma unroll
    for (int n = 0; n < 4; n++) bf[n] = *(const short8*)&Bl[(wc*64 + n*16 + l15)*32 + lhi*8];
#pragma unroll
    for (int m = 0; m < 4; m++)
#pragma unroll
      for (int n = 0; n < 4; n++)
        acc[m][n] = mfma16(af[m], bf[n], acc[m][n]);
  }

#pragma unroll
  for (int m = 0; m < 4; m++) {
#pragma unroll
    for (int n = 0; n < 4; n++) {
#pragma unroll
      for (int r = 0; r < 4; r++) {
        long i = i0 + wr*64 + m*16 + lhi*4 + r;       // token row
        int  j = (int)j0 + wc*64 + n*16 + l15;        // output feature
        float v = acc[m][n][r] + bias[j];
        if (MODE == 0) {
          int b = (int)(i >> 11), t = (int)(i & 2047);
          int sel = j >> 10, cc = j & 1023;
          int h = cc >> 6, d = cc & 63;
          long bh = (long)b * H_ + h;
          ushort bv = f2bf(v);
          if (sel == 0)      q [(bh*T_ + t)*D_ + d] = bv;
          else if (sel == 1) kk[(bh*T_ + t)*D_ + d] = bv;
          else               vt[(bh*D_ + d)*T_ + t] = bv;   // V stored transposed
        } else {
          outF[i * C_ + j] = v;
        }
      }
    }
  }
}

// ------------- causal flash attention, block-coop, counted vmcnt -------------
// 512 blocks x 512 threads (8 waves). Block bb: head = bb&63, i = bb>>6,
// J = i<4 ? i : 11-i (co-resident bb,bb+256 have complementary length).
// Two mirrored 128-row bands: low [128J,...], high [128(15-J),...]; wave w
// takes 16 rows of each. K[64][64] + Vt[64][64] double-buffered in LDS via
// global_load_lds (linear dest, inverse-XOR-swizzled global source; reads
// apply the same XOR -> conflict-free). Pipeline (T4): stage t+1 stays IN
// FLIGHT across the step-start barrier (s_waitcnt vmcnt(2), raw s_barrier,
// never vmcnt(0) in-loop); consume-done barrier, then stage t+2 overwrites
// the freed buffer. Swapped layouts: S'[kv][q]=mfma(K,Q); O'[d][q]=mfma(Vt,P).
#define SCALE_LOG2 0.18033688f   // (1/sqrt(64)) * log2(e)
#define PSTRIDE 36               // u32 stride per q-row (16B-aligned, padded)

// Online-softmax + bf16-pack for one 16-row group. sc is S'[kv][q] raw.
static __device__ __forceinline__ void softmax_pack(
    f32x4 sc[4], float& m, float& l, f32x4 o[4],
    int q0, int kv0, int l15, int lhi, uint* __restrict__ P)
{
  const bool needmask = (kv0 + 63 > q0);
  float sv[4][4];
  float pm = -1e30f;
#pragma unroll
  for (int c = 0; c < 4; c++)
#pragma unroll
    for (int r = 0; r < 4; r++) {
      float xv = sc[c][r] * SCALE_LOG2;
      if (needmask) {
        int kv = kv0 + c*16 + lhi*4 + r;
        if (kv > q0 + l15) xv = -1e30f;
      }
      sv[c][r] = xv;
      pm = fmaxf(pm, xv);
    }
  pm = fmaxf(pm, __shfl_xor(pm, 16));
  pm = fmaxf(pm, __shfl_xor(pm, 32));
  float nm = fmaxf(m, pm);
  float alpha = __builtin_amdgcn_exp2f(m - nm);
  m = nm;
  float ps = 0.f;
#pragma unroll
  for (int c = 0; c < 4; c++)
#pragma unroll
    for (int r = 0; r < 4; r++) {
      float p = __builtin_amdgcn_exp2f(sv[c][r] - nm);
      sv[c][r] = p;
      ps += p;
    }
  ps += __shfl_xor(ps, 16);
  ps += __shfl_xor(ps, 32);
  l = l * alpha + ps;
#pragma unroll
  for (int n = 0; n < 4; n++)
#pragma unroll
    for (int r = 0; r < 4; r++) o[n][r] *= alpha;
#pragma unroll
  for (int c = 0; c < 4; c++) {
    uint a, bq;
    asm("v_cvt_pk_bf16_f32 %0, %1, %2" : "=v"(a)  : "v"(sv[c][0]), "v"(sv[c][1]));
    asm("v_cvt_pk_bf16_f32 %0, %1, %2" : "=v"(bq) : "v"(sv[c][2]), "v"(sv[c][3]));
    uint2 pr; pr.x = a; pr.y = bq;
    *(uint2*)&P[l15 * PSTRIDE + c*8 + lhi*2] = pr;
  }
}

__global__ __launch_bounds__(512, 4) void attn_k(
    const ushort* __restrict__ Q, const ushort* __restrict__ K,
    const ushort* __restrict__ V, ushort* __restrict__ AO)
{
  __shared__ ushort Kt[2][64*64];
  __shared__ ushort Vt[2][64*64];
  __shared__ uint P2[16][16 * PSTRIDE];
  const int tid = threadIdx.x;
  const int lane = tid & 63;
  const int w = tid >> 6;
  const int l15 = lane & 15, lhi = lane >> 4;
  const int bb = blockIdx.x;
  const int head = bb & 63;                 // 8 heads per XCD (bb%8 = head%8)
  const int i = bb >> 6;                    // 0..7
  const int J = (i < 4) ? i : 11 - i;       // complementary pairing b, b+256
  const int nst = 32 - 2 * J;               // kv steps (>= 18)
  const int q0a = 128 * J + 16 * w;                 // low band rows
  const int q0b = 2048 - 128 * (J + 1) + 16 * w;    // high band rows

  const ushort* Qb = Q + (size_t)head * T_ * D_;
  const ushort* Kb = K + (size_t)head * T_ * D_;
  const ushort* Vb = V + (size_t)head * D_ * T_;   // [d][t]

  // Stage one kv-step: K tile [64][64] + Vt tile [64][64], 1 slot per thread
  // per tile. LDS dest linear; global source unit pre-XORed so a swizzled
  // read (unit ^ (row&7)) returns the natural layout.
  auto STAGE = [&](int buf, int kv0s) {
    const int srow = tid >> 3, su = tid & 7, gu = su ^ (srow & 7);
    ld16((const char*)Kb + ((size_t)(kv0s + srow) * D_ + gu * 8) * 2,
         (char*)&Kt[buf][0] + tid * 16);
    ld16((const char*)Vb + ((size_t)srow * T_ + kv0s + gu * 8) * 2,
         (char*)&Vt[buf][0] + tid * 16);
  };

  // Q as B-fragment (issued before staging; first vmcnt(2) retires these too)
  short8 qfa[2], qfb[2];
#pragma unroll
  for (int s = 0; s < 2; s++) {
    qfa[s] = *(const short8*)&Qb[(q0a + l15) * D_ + s * 32 + lhi * 8];
    qfb[s] = *(const short8*)&Qb[(q0b + l15) * D_ + s * 32 + lhi * 8];
  }

  f32x4 oa[4] = {}, ob[4] = {};   // O'[d][q]: d = n*16 + lhi*4 + r, q = l15
  float ma = -1e30f, la = 0.f, mb = -1e30f, lb = 0.f;

  STAGE(0, 0);
  STAGE(1, 64);                    // nst >= 18 > 1 always
  int cur = 0;

  for (int t = 0; t < nst; t++) {
    const int kv0 = t * 64;
    // Wait for stage t only; stage t+1's 2 loads stay in flight.
    if (t + 1 < nst) { asm volatile("s_waitcnt vmcnt(2)" ::: "memory"); }
    else             { asm volatile("s_waitcnt vmcnt(0)" ::: "memory"); }
    __builtin_amdgcn_s_barrier();
    __builtin_amdgcn_sched_barrier(0);

    const bool act_a = (kv0 <= q0a + 15);
    const bool act_b = (kv0 <= q0b + 15);

    // QK^T per k-slice (kf liveness = 4 fragments)
    f32x4 sca[4] = {}, scb[4] = {};
#pragma unroll
    for (int s = 0; s < 2; s++) {
      short8 kfs[4];
#pragma unroll
      for (int c = 0; c < 4; c++) {
        const int r = c*16 + l15, u = s*4 + lhi;
        kfs[c] = *(const short8*)&Kt[cur][r*64 + ((u ^ (r & 7)) << 3)];
      }
      __builtin_amdgcn_s_setprio(1);
      if (act_b) {
#pragma unroll
        for (int c = 0; c < 4; c++) scb[c] = mfma16(kfs[c], qfb[s], scb[c]);
      }
      if (act_a) {
#pragma unroll
        for (int c = 0; c < 4; c++) sca[c] = mfma16(kfs[c], qfa[s], sca[c]);
      }
      __builtin_amdgcn_s_setprio(0);
    }

    // V fragments issued early: latency hides under softmax.
    short8 vfr[4][2];
#pragma unroll
    for (int n = 0; n < 4; n++)
#pragma unroll
      for (int ks = 0; ks < 2; ks++) {
        const int r = n*16 + l15, u = ks*4 + lhi;
        vfr[n][ks] = *(const short8*)&Vt[cur][r*64 + ((u ^ (r & 7)) << 3)];
      }

    if (act_b) softmax_pack(scb, mb, lb, ob, q0b, kv0, l15, lhi, &P2[w*2][0]);
    if (act_a) softmax_pack(sca, ma, la, oa, q0a, kv0, l15, lhi, &P2[w*2+1][0]);

    asm volatile("s_waitcnt lgkmcnt(0)" ::: "memory");
    __builtin_amdgcn_sched_barrier(0);
    // B-fragment read: lane needs P[kv = ks*32 + lhi*8 + j][q = l15]
    short8 pfb[2], pfa[2];
    if (act_b) {
#pragma unroll
      for (int ks = 0; ks < 2; ks++) {
        uint4 pw = *(const uint4*)&P2[w*2][l15 * PSTRIDE + ks*16 + lhi*4];
        __builtin_memcpy(&pfb[ks], &pw, 16);
      }
    }
    if (act_a) {
#pragma unroll
      for (int ks = 0; ks < 2; ks++) {
        uint4 pw = *(const uint4*)&P2[w*2+1][l15 * PSTRIDE + ks*16 + lhi*4];
        __builtin_memcpy(&pfa[ks], &pw, 16);
      }
    }
    __builtin_amdgcn_s_setprio(1);
    if (act_b) {
#pragma unroll
      for (int n = 0; n < 4; n++) {
        ob[n] = mfma16(vfr[n][0], pfb[0], ob[n]);
        ob[n] = mfma16(vfr[n][1], pfb[1], ob[n]);
      }
    }
    if (act_a) {
#pragma unroll
      for (int n = 0; n < 4; n++) {
        oa[n] = mfma16(vfr[n][0], pfa[0], oa[n]);
        oa[n] = mfma16(vfr[n][1], pfa[1], oa[n]);
      }
    }
    __builtin_amdgcn_s_setprio(0);

    // Consume-done: all waves finished READING buf[cur] (every Kt/Vt ds_read
    // above was consumed by an MFMA before this point -> none outstanding).
    // NO vmcnt here: stage t+1 remains in flight.
    __builtin_amdgcn_s_barrier();
    __builtin_amdgcn_sched_barrier(0);
    if (t + 2 < nst) STAGE(cur, kv0 + 128);   // overwrite freed buffer
    cur ^= 1;
  }

  const int b = head >> 4, h = head & 15;
  {
    const float invl = 1.0f / lb;
    const size_t rowb = (size_t)(b * T_ + q0b + l15) * C_ + h * 64;
#pragma unroll
    for (int n = 0; n < 4; n++) {
      ushort4 ov;
      ov.x = f2bf(ob[n][0] * invl);
      ov.y = f2bf(ob[n][1] * invl);
      ov.z = f2bf(ob[n][2] * invl);
      ov.w = f2bf(ob[n][3] * invl);
      *(ushort4*)&AO[rowb + n*16 + lhi*4] = ov;
    }
  }
  {
    const float invl = 1.0f / la;
    const size_t rowb = (size_t)(b * T_ + q0a + l15) * C_ + h * 64;
#pragma unroll
    for (int n = 0; n < 4; n++) {
      ushort4 ov;
      ov.x = f2bf(oa[n][0] * invl);
      ov.y = f2bf(oa[n][1] * invl);
      ov.z = f2bf(oa[n][2] * invl);
      ov.w = f2bf(oa[n][3] * invl);
      *(ushort4*)&AO[rowb + n*16 + lhi*4] = ov;
    }
  }
}

extern "C" void kernel_launch(void* const* d_in, const int* in_sizes, int n_in,
                              void* d_out, int out_size, void* d_ws, size_t ws_size,
                              hipStream_t stream) {
  const float* x     = (const float*)d_in[0];
  const float* w_qkv = (const float*)d_in[1];
  const float* b_qkv = (const float*)d_in[2];
  const float* w_out = (const float*)d_in[3];
  const float* b_out = (const float*)d_in[4];
  float* out = (float*)d_out;

  ushort* xb    = (ushort*)d_ws;                    // 8192*1024
  ushort* wqkvb = xb    + (size_t)M_ * C_;          // 3072*1024
  ushort* woutb = wqkvb + (size_t)3 * C_ * C_;      // 1024*1024
  ushort* q     = woutb + (size_t)C_ * C_;          // [B,H,T,D]
  ushort* kk    = q     + (size_t)M_ * C_;          // [B,H,T,D]
  ushort* vt    = kk    + (size_t)M_ * C_;          // [B,H,D,T]
  ushort* ao    = xb;                               // reuse xb (free after QKV GEMM)

  cvt_bf16<<<1024, 256, 0, stream>>>(x,     xb,    (M_ * C_) / 4);
  cvt_bf16<<<512,  256, 0, stream>>>(w_qkv, wqkvb, (3 * C_ * C_) / 4);
  cvt_bf16<<<256,  256, 0, stream>>>(w_out, woutb, (C_ * C_) / 4);

  gemm_bt<0><<<dim3(3 * C_ / 128, M_ / 128), 256, 0, stream>>>(
      xb, wqkvb, b_qkv, C_, q, kk, vt, nullptr);

  // 8 waves x (16 low + 16 high) rows = 256 rows per block -> 512 blocks.
  attn_k<<<B_ * H_ * T_ / 256, 512, 0, stream>>>(q, kk, vt, ao);

  gemm_bt<1><<<dim3(C_ / 128, M_ / 128), 256, 0, stream>>>(
      ao, woutb, b_out, C_, nullptr, nullptr, nullptr, out);
}

// Round 8
// 302.561 us; speedup vs baseline: 1.0638x; 1.0638x over previous
//
#include <hip/hip_runtime.h>
#include <hip/hip_bf16.h>

// CausalSelfAttention: x[4,2048,1024] -> qkv proj -> 16-head causal attn -> out proj
// Pipeline: cvt(fp32->bf16) x3 -> gemm_bt<QKV> -> attn (block-coop staged,
// defer-max softmax, lane-partial l) -> gemm_bt<OUT>

#define B_ 4
#define T_ 2048
#define C_ 1024
#define H_ 16
#define D_ 64
#define M_ (B_*T_)   // 8192 tokens

#define SCALE_LOG2 0.18033688f   // (1/sqrt(64)) * log2(e), folded into Q in GEMM

typedef __attribute__((ext_vector_type(8))) short short8;
typedef __attribute__((ext_vector_type(4))) float f32x4;

static __device__ __forceinline__ ushort f2bf(float f) {
  __hip_bfloat16 b = __float2bfloat16(f);
  ushort u; __builtin_memcpy(&u, &b, 2); return u;
}

static __device__ __forceinline__ void ld16(const void* g, void* l) {
  __builtin_amdgcn_global_load_lds((const __attribute__((address_space(1))) void*)g,
                                   (__attribute__((address_space(3))) void*)l, 16, 0, 0);
}

static __device__ __forceinline__ f32x4 mfma16(short8 a, short8 b, f32x4 c) {
  return __builtin_amdgcn_mfma_f32_16x16x32_bf16(a, b, c, 0, 0, 0);
}

// ---------------- fp32 -> bf16 convert ----------------
__global__ void cvt_bf16(const float* __restrict__ in, ushort* __restrict__ out, int n4) {
  int i = blockIdx.x * blockDim.x + threadIdx.x;
  int st = gridDim.x * blockDim.x;
  for (; i < n4; i += st) {
    float4 v = ((const float4*)in)[i];
    ushort4 o;
    o.x = f2bf(v.x); o.y = f2bf(v.y); o.z = f2bf(v.z); o.w = f2bf(v.w);
    ((ushort4*)out)[i] = o;
  }
}

// ---------------- C = A @ B^T + bias (both A,B K-major bf16) ----------------
// MODE 0: QKV projection -> scatter to q[B,H,T,D] (pre-scaled by SCALE_LOG2),
//         k[B,H,T,D], vt[B,H,D,T] (bf16)
// MODE 1: out projection -> fp32 d_out
template<int MODE>
__global__ __launch_bounds__(256) void gemm_bt(
    const ushort* __restrict__ A, const ushort* __restrict__ Bm,
    const float* __restrict__ bias, int K,
    ushort* __restrict__ q, ushort* __restrict__ kk, ushort* __restrict__ vt,
    float* __restrict__ outF)
{
  __shared__ ushort Al[128*32];
  __shared__ ushort Bl[128*32];
  const int tid = threadIdx.x;
  const int lane = tid & 63;
  const int w = tid >> 6;
  const int wr = w >> 1, wc = w & 1;
  const int l15 = lane & 15, lhi = lane >> 4;
  const long i0 = (long)blockIdx.y * 128;
  const long j0 = (long)blockIdx.x * 128;

  f32x4 acc[4][4] = {};

  for (int k0 = 0; k0 < K; k0 += 32) {
    __syncthreads();
    {
      int c = tid;
      ld16((const char*)A  + ((i0 + (c >> 2)) * K + k0 + (c & 3) * 8) * 2, (char*)Al + c * 16);
      ld16((const char*)Bm + ((j0 + (c >> 2)) * K + k0 + (c & 3) * 8) * 2, (char*)Bl + c * 16);
      c = tid + 256;
      ld16((const char*)A  + ((i0 + (c >> 2)) * K + k0 + (c & 3) * 8) * 2, (char*)Al + c * 16);
      ld16((const char*)Bm + ((j0 + (c >> 2)) * K + k0 + (c & 3) * 8) * 2, (char*)Bl + c * 16);
    }
    __syncthreads();
    short8 af[4], bf[4];
#pragma unroll
    for (int m = 0; m < 4; m++) af[m] = *(const short8*)&Al[(wr*64 + m*16 + l15)*32 + lhi*8];
#pragma unroll
    for (int n = 0; n < 4; n++) bf[n] = *(const short8*)&Bl[(wc*64 + n*16 + l15)*32 + lhi*8];
#pragma unroll
    for (int m = 0; m < 4; m++)
#pragma unroll
      for (int n = 0; n < 4; n++)
        acc[m][n] = mfma16(af[m], bf[n], acc[m][n]);
  }

#pragma unroll
  for (int m = 0; m < 4; m++) {
#pragma unroll
    for (int n = 0; n < 4; n++) {
#pragma unroll
      for (int r = 0; r < 4; r++) {
        long i = i0 + wr*64 + m*16 + lhi*4 + r;       // token row
        int  j = (int)j0 + wc*64 + n*16 + l15;        // output feature
        float v = acc[m][n][r] + bias[j];
        if (MODE == 0) {
          int b = (int)(i >> 11), t = (int)(i & 2047);
          int sel = j >> 10, cc = j & 1023;
          int h = cc >> 6, d = cc & 63;
          long bh = (long)b * H_ + h;
          if (sel == 0)      q [(bh*T_ + t)*D_ + d] = f2bf(v * SCALE_LOG2);
          else if (sel == 1) kk[(bh*T_ + t)*D_ + d] = f2bf(v);
          else               vt[(bh*D_ + d)*T_ + t] = f2bf(v);  // V transposed
        } else {
          outF[i * C_ + j] = v;
        }
      }
    }
  }
}

// ------------- causal flash attention, block-coop, defer-max -------------
// 512 blocks x 512 threads (8 waves). Block bb: head = bb&63, i = bb>>6,
// J = i<4 ? i : 11-i (co-resident bb,bb+256 have complementary length).
// Two mirrored 128-row bands; wave w takes 16 rows of each. K[64][64] +
// Vt[64][64] double-buffered in LDS via global_load_lds (linear dest,
// inverse-XOR-swizzled global source; reads apply same XOR). Counted-vmcnt
// pipeline. Softmax: Q pre-scaled to exp2 domain; running max m deferred
// (rescale only when __any(pmax > m+8), no cross-lane ops in common path);
// l kept lane-partial, reduced once in epilogue.
// Swapped layouts: S'[kv][q]=mfma(K,Q); O'[d][q]=mfma(Vt,P).
#define PSTRIDE 36               // u32 stride per q-row (16B-aligned, padded)

// Defer-max online softmax + bf16-pack for one 16-row group.
// sc = S'[kv][q] already in exp2 domain. m: row max (row-consistent),
// lp: lane-partial sum, o: unnormalized output.
static __device__ __forceinline__ void softmax_pack(
    f32x4 sc[4], float& m, float& lp, f32x4 (&o)[4],
    int q0, int kv0, int l15, int lhi, uint* __restrict__ P)
{
  const bool needmask = (kv0 + 63 > q0);
  float sv[4][4];
#pragma unroll
  for (int c = 0; c < 4; c++)
#pragma unroll
    for (int r = 0; r < 4; r++) {
      float xv = sc[c][r];
      if (needmask) {
        int kv = kv0 + c*16 + lhi*4 + r;
        if (kv > q0 + l15) xv = -1e30f;
      }
      sv[c][r] = xv;
    }
  // lane-local max (tree)
  float c0 = fmaxf(fmaxf(sv[0][0], sv[0][1]), fmaxf(sv[0][2], sv[0][3]));
  float c1 = fmaxf(fmaxf(sv[1][0], sv[1][1]), fmaxf(sv[1][2], sv[1][3]));
  float c2 = fmaxf(fmaxf(sv[2][0], sv[2][1]), fmaxf(sv[2][2], sv[2][3]));
  float c3 = fmaxf(fmaxf(sv[3][0], sv[3][1]), fmaxf(sv[3][2], sv[3][3]));
  float pmax = fmaxf(fmaxf(c0, c1), fmaxf(c2, c3));
  // Rare rescale path: only when some lane exceeds the slack bound.
  if (__any(pmax > m + 8.0f)) {
    float pm = pmax;
    pm = fmaxf(pm, __shfl_xor(pm, 16));
    pm = fmaxf(pm, __shfl_xor(pm, 32));
    float nm = fmaxf(m, pm);
    float alpha = __builtin_amdgcn_exp2f(m - nm);
    m = nm;
    lp *= alpha;
#pragma unroll
    for (int n = 0; n < 4; n++)
#pragma unroll
      for (int r = 0; r < 4; r++) o[n][r] *= alpha;
  }
  // P = exp2(sv - m), lane-partial sum (tree), pack to bf16 pairs.
  float t0, t1, t2, t3;
#pragma unroll
  for (int c = 0; c < 4; c++) {
    float p0 = __builtin_amdgcn_exp2f(sv[c][0] - m);
    float p1 = __builtin_amdgcn_exp2f(sv[c][1] - m);
    float p2 = __builtin_amdgcn_exp2f(sv[c][2] - m);
    float p3 = __builtin_amdgcn_exp2f(sv[c][3] - m);
    sv[c][0] = p0; sv[c][1] = p1; sv[c][2] = p2; sv[c][3] = p3;
    float t = (p0 + p1) + (p2 + p3);
    if (c == 0) t0 = t; else if (c == 1) t1 = t; else if (c == 2) t2 = t; else t3 = t;
  }
  lp += (t0 + t1) + (t2 + t3);
#pragma unroll
  for (int c = 0; c < 4; c++) {
    uint a, bq;
    asm("v_cvt_pk_bf16_f32 %0, %1, %2" : "=v"(a)  : "v"(sv[c][0]), "v"(sv[c][1]));
    asm("v_cvt_pk_bf16_f32 %0, %1, %2" : "=v"(bq) : "v"(sv[c][2]), "v"(sv[c][3]));
    uint2 pr; pr.x = a; pr.y = bq;
    *(uint2*)&P[l15 * PSTRIDE + c*8 + lhi*2] = pr;
  }
}

__global__ __launch_bounds__(512, 4) void attn_k(
    const ushort* __restrict__ Q, const ushort* __restrict__ K,
    const ushort* __restrict__ V, ushort* __restrict__ AO)
{
  __shared__ ushort Kt[2][64*64];
  __shared__ ushort Vt[2][64*64];
  __shared__ uint P2[16][16 * PSTRIDE];
  const int tid = threadIdx.x;
  const int lane = tid & 63;
  const int w = tid >> 6;
  const int l15 = lane & 15, lhi = lane >> 4;
  const int bb = blockIdx.x;
  const int head = bb & 63;                 // 8 heads per XCD (bb%8 = head%8)
  const int i = bb >> 6;                    // 0..7
  const int J = (i < 4) ? i : 11 - i;       // complementary pairing b, b+256
  const int nst = 32 - 2 * J;               // kv steps (>= 18)
  const int q0a = 128 * J + 16 * w;                 // low band rows
  const int q0b = 2048 - 128 * (J + 1) + 16 * w;    // high band rows

  const ushort* Qb = Q + (size_t)head * T_ * D_;
  const ushort* Kb = K + (size_t)head * T_ * D_;
  const ushort* Vb = V + (size_t)head * D_ * T_;   // [d][t]

  auto STAGE = [&](int buf, int kv0s) {
    const int srow = tid >> 3, su = tid & 7, gu = su ^ (srow & 7);
    ld16((const char*)Kb + ((size_t)(kv0s + srow) * D_ + gu * 8) * 2,
         (char*)&Kt[buf][0] + tid * 16);
    ld16((const char*)Vb + ((size_t)srow * T_ + kv0s + gu * 8) * 2,
         (char*)&Vt[buf][0] + tid * 16);
  };

  // Q as B-fragment (Q already in exp2 domain from the GEMM epilogue).
  short8 qfa[2], qfb[2];
#pragma unroll
  for (int s = 0; s < 2; s++) {
    qfa[s] = *(const short8*)&Qb[(q0a + l15) * D_ + s * 32 + lhi * 8];
    qfb[s] = *(const short8*)&Qb[(q0b + l15) * D_ + s * 32 + lhi * 8];
  }

  f32x4 oa[4] = {}, ob[4] = {};   // O'[d][q]: d = n*16 + lhi*4 + r, q = l15
  float ma = -1e30f, la = 0.f, mb = -1e30f, lb = 0.f;

  STAGE(0, 0);
  STAGE(1, 64);                    // nst >= 18 > 1 always
  int cur = 0;

  for (int t = 0; t < nst; t++) {
    const int kv0 = t * 64;
    // Wait for stage t only; stage t+1's 2 loads stay in flight.
    if (t + 1 < nst) { asm volatile("s_waitcnt vmcnt(2)" ::: "memory"); }
    else             { asm volatile("s_waitcnt vmcnt(0)" ::: "memory"); }
    __builtin_amdgcn_s_barrier();
    __builtin_amdgcn_sched_barrier(0);

    const bool act_a = (kv0 <= q0a + 15);
    const bool act_b = (kv0 <= q0b + 15);

    // QK^T per k-slice (kf liveness = 4 fragments)
    f32x4 sca[4] = {}, scb[4] = {};
#pragma unroll
    for (int s = 0; s < 2; s++) {
      short8 kfs[4];
#pragma unroll
      for (int c = 0; c < 4; c++) {
        const int r = c*16 + l15, u = s*4 + lhi;
        kfs[c] = *(const short8*)&Kt[cur][r*64 + ((u ^ (r & 7)) << 3)];
      }
      __builtin_amdgcn_s_setprio(1);
      if (act_b) {
#pragma unroll
        for (int c = 0; c < 4; c++) scb[c] = mfma16(kfs[c], qfb[s], scb[c]);
      }
      if (act_a) {
#pragma unroll
        for (int c = 0; c < 4; c++) sca[c] = mfma16(kfs[c], qfa[s], sca[c]);
      }
      __builtin_amdgcn_s_setprio(0);
    }

    // V fragments issued early: latency hides under softmax.
    short8 vfr[4][2];
#pragma unroll
    for (int n = 0; n < 4; n++)
#pragma unroll
      for (int ks = 0; ks < 2; ks++) {
        const int r = n*16 + l15, u = ks*4 + lhi;
        vfr[n][ks] = *(const short8*)&Vt[cur][r*64 + ((u ^ (r & 7)) << 3)];
      }

    if (act_b) softmax_pack(scb, mb, lb, ob, q0b, kv0, l15, lhi, &P2[w*2][0]);
    if (act_a) softmax_pack(sca, ma, la, oa, q0a, kv0, l15, lhi, &P2[w*2+1][0]);

    asm volatile("s_waitcnt lgkmcnt(0)" ::: "memory");
    __builtin_amdgcn_sched_barrier(0);
    // B-fragment read: lane needs P[kv = ks*32 + lhi*8 + j][q = l15]
    short8 pfb[2], pfa[2];
    if (act_b) {
#pragma unroll
      for (int ks = 0; ks < 2; ks++) {
        uint4 pw = *(const uint4*)&P2[w*2][l15 * PSTRIDE + ks*16 + lhi*4];
        __builtin_memcpy(&pfb[ks], &pw, 16);
      }
    }
    if (act_a) {
#pragma unroll
      for (int ks = 0; ks < 2; ks++) {
        uint4 pw = *(const uint4*)&P2[w*2+1][l15 * PSTRIDE + ks*16 + lhi*4];
        __builtin_memcpy(&pfa[ks], &pw, 16);
      }
    }
    __builtin_amdgcn_s_setprio(1);
    if (act_b) {
#pragma unroll
      for (int n = 0; n < 4; n++) {
        ob[n] = mfma16(vfr[n][0], pfb[0], ob[n]);
        ob[n] = mfma16(vfr[n][1], pfb[1], ob[n]);
      }
    }
    if (act_a) {
#pragma unroll
      for (int n = 0; n < 4; n++) {
        oa[n] = mfma16(vfr[n][0], pfa[0], oa[n]);
        oa[n] = mfma16(vfr[n][1], pfa[1], oa[n]);
      }
    }
    __builtin_amdgcn_s_setprio(0);

    // Consume-done barrier; stage t+1 remains in flight (no vmcnt here).
    __builtin_amdgcn_s_barrier();
    __builtin_amdgcn_sched_barrier(0);
    if (t + 2 < nst) STAGE(cur, kv0 + 128);   // overwrite freed buffer
    cur ^= 1;
  }

  const int b = head >> 4, h = head & 15;
  {
    float l = lb;
    l += __shfl_xor(l, 16); l += __shfl_xor(l, 32);
    const float invl = 1.0f / l;
    const size_t rowb = (size_t)(b * T_ + q0b + l15) * C_ + h * 64;
#pragma unroll
    for (int n = 0; n < 4; n++) {
      ushort4 ov;
      ov.x = f2bf(ob[n][0] * invl);
      ov.y = f2bf(ob[n][1] * invl);
      ov.z = f2bf(ob[n][2] * invl);
      ov.w = f2bf(ob[n][3] * invl);
      *(ushort4*)&AO[rowb + n*16 + lhi*4] = ov;
    }
  }
  {
    float l = la;
    l += __shfl_xor(l, 16); l += __shfl_xor(l, 32);
    const float invl = 1.0f / l;
    const size_t rowb = (size_t)(b * T_ + q0a + l15) * C_ + h * 64;
#pragma unroll
    for (int n = 0; n < 4; n++) {
      ushort4 ov;
      ov.x = f2bf(oa[n][0] * invl);
      ov.y = f2bf(oa[n][1] * invl);
      ov.z = f2bf(oa[n][2] * invl);
      ov.w = f2bf(oa[n][3] * invl);
      *(ushort4*)&AO[rowb + n*16 + lhi*4] = ov;
    }
  }
}

extern "C" void kernel_launch(void* const* d_in, const int* in_sizes, int n_in,
                              void* d_out, int out_size, void* d_ws, size_t ws_size,
                              hipStream_t stream) {
  const float* x     = (const float*)d_in[0];
  const float* w_qkv = (const float*)d_in[1];
  const float* b_qkv = (const float*)d_in[2];
  const float* w_out = (const float*)d_in[3];
  const float* b_out = (const float*)d_in[4];
  float* out = (float*)d_out;

  ushort* xb    = (ushort*)d_ws;                    // 8192*1024
  ushort* wqkvb = xb    + (size_t)M_ * C_;          // 3072*1024
  ushort* woutb = wqkvb + (size_t)3 * C_ * C_;      // 1024*1024
  ushort* q     = woutb + (size_t)C_ * C_;          // [B,H,T,D] (exp2-domain scaled)
  ushort* kk    = q     + (size_t)M_ * C_;          // [B,H,T,D]
  ushort* vt    = kk    + (size_t)M_ * C_;          // [B,H,D,T]
  ushort* ao    = xb;                               // reuse xb (free after QKV GEMM)

  cvt_bf16<<<1024, 256, 0, stream>>>(x,     xb,    (M_ * C_) / 4);
  cvt_bf16<<<512,  256, 0, stream>>>(w_qkv, wqkvb, (3 * C_ * C_) / 4);
  cvt_bf16<<<256,  256, 0, stream>>>(w_out, woutb, (C_ * C_) / 4);

  gemm_bt<0><<<dim3(3 * C_ / 128, M_ / 128), 256, 0, stream>>>(
      xb, wqkvb, b_qkv, C_, q, kk, vt, nullptr);

  // 8 waves x (16 low + 16 high) rows = 256 rows per block -> 512 blocks.
  attn_k<<<B_ * H_ * T_ / 256, 512, 0, stream>>>(q, kk, vt, ao);

  gemm_bt<1><<<dim3(C_ / 128, M_ / 128), 256, 0, stream>>>(
      ao, woutb, b_out, C_, nullptr, nullptr, nullptr, out);
}

// Round 12
// 219.053 us; speedup vs baseline: 1.4693x; 1.3812x over previous
//
#include <hip/hip_runtime.h>
#include <hip/hip_bf16.h>

// CausalSelfAttention: x[4,2048,1024] -> qkv proj -> 16-head causal attn -> out proj
// Pipeline: cvt(fp32->bf16) x3 -> gemm_bt<QKV> -> attn (32x32 MFMA, in-register
// softmax with shfl pair-reduce, wave-private LDS P relayout) -> gemm_bt<OUT>
// R12 = R11 with permlane32_swap asm replaced by __shfl_xor(,32) (isolation).

#define B_ 4
#define T_ 2048
#define C_ 1024
#define H_ 16
#define D_ 64
#define M_ (B_*T_)   // 8192 tokens

#define SCALE_LOG2 0.18033688f   // (1/sqrt(64)) * log2(e), folded into Q in GEMM

typedef __attribute__((ext_vector_type(8))) short short8;
typedef __attribute__((ext_vector_type(4))) float f32x4;
typedef __attribute__((ext_vector_type(16))) float f32x16;

static __device__ __forceinline__ ushort f2bf(float f) {
  __hip_bfloat16 b = __float2bfloat16(f);
  ushort u; __builtin_memcpy(&u, &b, 2); return u;
}

static __device__ __forceinline__ void ld16(const void* g, void* l) {
  __builtin_amdgcn_global_load_lds((const __attribute__((address_space(1))) void*)g,
                                   (__attribute__((address_space(3))) void*)l, 16, 0, 0);
}

static __device__ __forceinline__ f32x4 mfma16(short8 a, short8 b, f32x4 c) {
  return __builtin_amdgcn_mfma_f32_16x16x32_bf16(a, b, c, 0, 0, 0);
}
static __device__ __forceinline__ f32x16 mfma32(short8 a, short8 b, f32x16 c) {
  return __builtin_amdgcn_mfma_f32_32x32x16_bf16(a, b, c, 0, 0, 0);
}

// Pair reduce across (lane, lane+32) via known-good shuffle.
static __device__ __forceinline__ float pair_max(float x) {
  return fmaxf(x, __shfl_xor(x, 32));
}
static __device__ __forceinline__ float pair_sum(float x) {
  return x + __shfl_xor(x, 32);
}

// ---------------- fp32 -> bf16 convert ----------------
__global__ void cvt_bf16(const float* __restrict__ in, ushort* __restrict__ out, int n4) {
  int i = blockIdx.x * blockDim.x + threadIdx.x;
  int st = gridDim.x * blockDim.x;
  for (; i < n4; i += st) {
    float4 v = ((const float4*)in)[i];
    ushort4 o;
    o.x = f2bf(v.x); o.y = f2bf(v.y); o.z = f2bf(v.z); o.w = f2bf(v.w);
    ((ushort4*)out)[i] = o;
  }
}

// ---------------- C = A @ B^T + bias (both A,B K-major bf16) ----------------
// MODE 0: QKV projection -> scatter to q[B,H,T,D] (pre-scaled by SCALE_LOG2),
//         k[B,H,T,D], vt[B,H,D,T] (bf16)
// MODE 1: out projection -> fp32 d_out
template<int MODE>
__global__ __launch_bounds__(256) void gemm_bt(
    const ushort* __restrict__ A, const ushort* __restrict__ Bm,
    const float* __restrict__ bias, int K,
    ushort* __restrict__ q, ushort* __restrict__ kk, ushort* __restrict__ vt,
    float* __restrict__ outF)
{
  __shared__ ushort Al[128*32];
  __shared__ ushort Bl[128*32];
  const int tid = threadIdx.x;
  const int lane = tid & 63;
  const int w = tid >> 6;
  const int wr = w >> 1, wc = w & 1;
  const int l15 = lane & 15, lhi = lane >> 4;
  const long i0 = (long)blockIdx.y * 128;
  const long j0 = (long)blockIdx.x * 128;

  f32x4 acc[4][4] = {};

  for (int k0 = 0; k0 < K; k0 += 32) {
    __syncthreads();
    {
      int c = tid;
      ld16((const char*)A  + ((i0 + (c >> 2)) * K + k0 + (c & 3) * 8) * 2, (char*)Al + c * 16);
      ld16((const char*)Bm + ((j0 + (c >> 2)) * K + k0 + (c & 3) * 8) * 2, (char*)Bl + c * 16);
      c = tid + 256;
      ld16((const char*)A  + ((i0 + (c >> 2)) * K + k0 + (c & 3) * 8) * 2, (char*)Al + c * 16);
      ld16((const char*)Bm + ((j0 + (c >> 2)) * K + k0 + (c & 3) * 8) * 2, (char*)Bl + c * 16);
    }
    __syncthreads();
    short8 af[4], bf[4];
#pragma unroll
    for (int m = 0; m < 4; m++) af[m] = *(const short8*)&Al[(wr*64 + m*16 + l15)*32 + lhi*8];
#pragma unroll
    for (int n = 0; n < 4; n++) bf[n] = *(const short8*)&Bl[(wc*64 + n*16 + l15)*32 + lhi*8];
#pragma unroll
    for (int m = 0; m < 4; m++)
#pragma unroll
      for (int n = 0; n < 4; n++)
        acc[m][n] = mfma16(af[m], bf[n], acc[m][n]);
  }

#pragma unroll
  for (int m = 0; m < 4; m++) {
#pragma unroll
    for (int n = 0; n < 4; n++) {
#pragma unroll
      for (int r = 0; r < 4; r++) {
        long i = i0 + wr*64 + m*16 + lhi*4 + r;       // token row
        int  j = (int)j0 + wc*64 + n*16 + l15;        // output feature
        float v = acc[m][n][r] + bias[j];
        if (MODE == 0) {
          int b = (int)(i >> 11), t = (int)(i & 2047);
          int sel = j >> 10, cc = j & 1023;
          int h = cc >> 6, d = cc & 63;
          long bh = (long)b * H_ + h;
          if (sel == 0)      q [(bh*T_ + t)*D_ + d] = f2bf(v * SCALE_LOG2);
          else if (sel == 1) kk[(bh*T_ + t)*D_ + d] = f2bf(v);
          else               vt[(bh*D_ + d)*T_ + t] = f2bf(v);  // V transposed
        } else {
          outF[i * C_ + j] = v;
        }
      }
    }
  }
}

// ------------- causal flash attention, 32x32 MFMA, LDS-P relayout -------------
// 512 blocks x 256 threads (4 waves). head = bb&63 (8 heads/XCD), i = bb>>6,
// J = i<4 ? i : 11-i (co-resident bb, bb+256 sum to constant work).
// Wave w: low rows [128J+32w, +31], high rows mirror. KVBLK=64 staged
// double-buffered (counted vmcnt, XOR granule swizzle).
// QK^T = mfma32(K, Q): lane(q=l31,hi) holds S[kv=(r&3)+8(r>>2)+4hi+32c][q].
// Softmax in-register: exact row max (shfl pair reduce), unconditional
// rescale, lane-partial l. P -> bf16 pairs -> wave-private LDS (stride 20
// u32/row) -> uint4 B-fragment reads. PV = mfma32(Vt, P) -> O'[d][q].
#define PSTR 20   // u32 per q-row: 16 pairs + 4 pad

static __device__ __forceinline__ void softmax_pack32(
    f32x16& sc, float& m, float& lp, f32x16 (&o)[2],
    int q0, int kvbase, int l31, int hi, uint* __restrict__ P)
{
  float sv[16];
  const bool needmask = (kvbase + 31 > q0);
#pragma unroll
  for (int r = 0; r < 16; r++) {
    float xv = sc[r];
    if (needmask) {
      int kv = kvbase + (r & 3) + 8 * (r >> 2) + 4 * hi;
      if (kv > q0 + l31) xv = -1e30f;
    }
    sv[r] = xv;
  }
  // exact row max: in-lane tree + pair reduce
  float p0 = fmaxf(fmaxf(sv[0], sv[1]),  fmaxf(sv[2], sv[3]));
  float p1 = fmaxf(fmaxf(sv[4], sv[5]),  fmaxf(sv[6], sv[7]));
  float p2 = fmaxf(fmaxf(sv[8], sv[9]),  fmaxf(sv[10], sv[11]));
  float p3 = fmaxf(fmaxf(sv[12], sv[13]), fmaxf(sv[14], sv[15]));
  float pm = fmaxf(fmaxf(p0, p1), fmaxf(p2, p3));
  float rowm = pair_max(pm);
  // unconditional rescale
  float nm = fmaxf(m, rowm);
  float alpha = __builtin_amdgcn_exp2f(m - nm);
  m = nm;
  lp *= alpha;
#pragma unroll
  for (int dt = 0; dt < 2; dt++)
#pragma unroll
    for (int r = 0; r < 16; r++) o[dt][r] *= alpha;
  float s = 0.f;
#pragma unroll
  for (int r = 0; r < 16; r++) {
    float p = __builtin_amdgcn_exp2f(sv[r] - m);
    sv[r] = p;
    s += p;
  }
  lp += s;
  // pack pairs (kv 2j, 2j+1) and store: W[j] -> pair pos 4*(j>>1)+(j&1)+2hi
  uint W[8];
#pragma unroll
  for (int r = 0; r < 8; r++)
    asm("v_cvt_pk_bf16_f32 %0, %1, %2" : "=v"(W[r]) : "v"(sv[2*r]), "v"(sv[2*r+1]));
#pragma unroll
  for (int r2 = 0; r2 < 4; r2++) {
    uint2 pr; pr.x = W[2*r2]; pr.y = W[2*r2 + 1];
    *(uint2*)&P[l31 * PSTR + r2*4 + 2*hi] = pr;
  }
}

__global__ __launch_bounds__(256, 2) void attn_k(
    const ushort* __restrict__ Q, const ushort* __restrict__ K,
    const ushort* __restrict__ V, ushort* __restrict__ AO)
{
  __shared__ ushort Kt[2][64*64];
  __shared__ ushort Vt[2][64*64];
  __shared__ uint P2[8][32 * PSTR];    // [wave*2 + group][q-row][pair]
  const int tid = threadIdx.x;
  const int lane = tid & 63;
  const int w = tid >> 6;              // 0..3
  const int l31 = lane & 31, hi = lane >> 5;
  const int bb = blockIdx.x;
  const int head = bb & 63;
  const int i = bb >> 6;               // 0..7
  const int J = (i < 4) ? i : 11 - i;
  const int nst = 32 - 2 * J;          // kv steps (>= 18)
  const int q0a = 128 * J + 32 * w;            // low band
  const int q0b = 2016 - 128 * J - 32 * w;     // high (mirror) band

  const ushort* Qb = Q + (size_t)head * T_ * D_;
  const ushort* Kb = K + (size_t)head * T_ * D_;
  const ushort* Vb = V + (size_t)head * D_ * T_;   // [d][t]

  auto STAGE = [&](int buf, int kv0s) {
#pragma unroll
    for (int hb = 0; hb < 2; hb++) {
      int slot = tid + hb * 256;            // 0..511
      int row = slot >> 3, g = slot & 7, gs = g ^ (row & 7);
      ld16((const char*)Kb + ((size_t)(kv0s + row) * D_ + gs * 8) * 2,
           (char*)&Kt[buf][0] + slot * 16);
      ld16((const char*)Vb + ((size_t)row * T_ + kv0s + gs * 8) * 2,
           (char*)&Vt[buf][0] + slot * 16);
    }
  };

  // Q as B-fragment: lane holds Q[q0+l31][d = s*16 + hi*8 + e] per slice s.
  short8 qfa[4], qfb[4];
#pragma unroll
  for (int s = 0; s < 4; s++) {
    qfa[s] = *(const short8*)&Qb[(q0a + l31) * D_ + s*16 + hi*8];
    qfb[s] = *(const short8*)&Qb[(q0b + l31) * D_ + s*16 + hi*8];
  }

  f32x16 oa[2] = {}, ob[2] = {};       // O'[d][q]: d = dt*32 + (r&3)+8(r>>2)+4hi
  float ma = -1e30f, la = 0.f, mb = -1e30f, lb = 0.f;

  STAGE(0, 0);
  STAGE(1, 64);
  int cur = 0;

  for (int t = 0; t < nst; t++) {
    const int kv0 = t * 64;
    if (t + 1 < nst) { asm volatile("s_waitcnt vmcnt(4)" ::: "memory"); }
    else             { asm volatile("s_waitcnt vmcnt(0)" ::: "memory"); }
    __builtin_amdgcn_s_barrier();
    __builtin_amdgcn_sched_barrier(0);

#pragma unroll
    for (int c = 0; c < 2; c++) {
      const int kvc = kv0 + 32 * c;
      const bool act_b = (kvc <= q0b + 31);
      const bool act_a = (kvc <= q0a + 31);   // act_a implies act_b
      if (act_b) {
        // K A-fragment: lane holds K[c*32+l31][d = s*16 + hi*8 + e]
        short8 kf[4];
#pragma unroll
        for (int s = 0; s < 4; s++) {
          const int row = c*32 + l31;
          kf[s] = *(const short8*)&Kt[cur][row*64 + (((2*s + hi) ^ (row & 7)) << 3)];
        }
        f32x16 scb = {}, sca = {};
        __builtin_amdgcn_s_setprio(1);
#pragma unroll
        for (int s = 0; s < 4; s++) scb = mfma32(kf[s], qfb[s], scb);
        if (act_a) {
#pragma unroll
          for (int s = 0; s < 4; s++) sca = mfma32(kf[s], qfa[s], sca);
        }
        __builtin_amdgcn_s_setprio(0);

        // Vt A-fragment for slices sl=0,1: Vt[dt*32+l31][kv = c*32+sl*16+hi*8+e]
        short8 vf[2][2];
#pragma unroll
        for (int sl = 0; sl < 2; sl++)
#pragma unroll
          for (int dt = 0; dt < 2; dt++) {
            const int row = dt*32 + l31;
            vf[sl][dt] = *(const short8*)
                &Vt[cur][row*64 + (((2*(2*c + sl) + hi) ^ (row & 7)) << 3)];
          }

        softmax_pack32(scb, mb, lb, ob, q0b, kvc, l31, hi, &P2[w*2][0]);
        if (act_a) softmax_pack32(sca, ma, la, oa, q0a, kvc, l31, hi, &P2[w*2+1][0]);

        asm volatile("s_waitcnt lgkmcnt(0)" ::: "memory");
        __builtin_amdgcn_sched_barrier(0);
        // B-fragment read: lane (l31,hi) needs pairs sl*8 + hi*4 + {0..3}
        short8 pfb[2], pfa[2];
#pragma unroll
        for (int sl = 0; sl < 2; sl++) {
          uint4 pw = *(const uint4*)&P2[w*2][l31 * PSTR + sl*8 + hi*4];
          __builtin_memcpy(&pfb[sl], &pw, 16);
        }
        if (act_a) {
#pragma unroll
          for (int sl = 0; sl < 2; sl++) {
            uint4 pw = *(const uint4*)&P2[w*2+1][l31 * PSTR + sl*8 + hi*4];
            __builtin_memcpy(&pfa[sl], &pw, 16);
          }
        }
        __builtin_amdgcn_s_setprio(1);
#pragma unroll
        for (int sl = 0; sl < 2; sl++)
#pragma unroll
          for (int dt = 0; dt < 2; dt++)
            ob[dt] = mfma32(vf[sl][dt], pfb[sl], ob[dt]);
        if (act_a) {
#pragma unroll
          for (int sl = 0; sl < 2; sl++)
#pragma unroll
            for (int dt = 0; dt < 2; dt++)
              oa[dt] = mfma32(vf[sl][dt], pfa[sl], oa[dt]);
        }
        __builtin_amdgcn_s_setprio(0);
      }
    }

    __builtin_amdgcn_s_barrier();
    __builtin_amdgcn_sched_barrier(0);
    if (t + 2 < nst) STAGE(cur, kv0 + 128);   // overwrite freed buffer
    cur ^= 1;
  }

  const int b = head >> 4, h = head & 15;
  {
    const float invl = 1.0f / pair_sum(lb);
    const size_t rowb = (size_t)(b * T_ + q0b + l31) * C_ + h * 64;
#pragma unroll
    for (int dt = 0; dt < 2; dt++)
#pragma unroll
      for (int rg = 0; rg < 4; rg++) {
        const int d0 = dt*32 + 8*rg + 4*hi;
        ushort4 ov;
        ov.x = f2bf(ob[dt][rg*4+0] * invl);
        ov.y = f2bf(ob[dt][rg*4+1] * invl);
        ov.z = f2bf(ob[dt][rg*4+2] * invl);
        ov.w = f2bf(ob[dt][rg*4+3] * invl);
        *(ushort4*)&AO[rowb + d0] = ov;
      }
  }
  {
    const float invl = 1.0f / pair_sum(la);
    const size_t rowb = (size_t)(b * T_ + q0a + l31) * C_ + h * 64;
#pragma unroll
    for (int dt = 0; dt < 2; dt++)
#pragma unroll
      for (int rg = 0; rg < 4; rg++) {
        const int d0 = dt*32 + 8*rg + 4*hi;
        ushort4 ov;
        ov.x = f2bf(oa[dt][rg*4+0] * invl);
        ov.y = f2bf(oa[dt][rg*4+1] * invl);
        ov.z = f2bf(oa[dt][rg*4+2] * invl);
        ov.w = f2bf(oa[dt][rg*4+3] * invl);
        *(ushort4*)&AO[rowb + d0] = ov;
      }
  }
}

extern "C" void kernel_launch(void* const* d_in, const int* in_sizes, int n_in,
                              void* d_out, int out_size, void* d_ws, size_t ws_size,
                              hipStream_t stream) {
  const float* x     = (const float*)d_in[0];
  const float* w_qkv = (const float*)d_in[1];
  const float* b_qkv = (const float*)d_in[2];
  const float* w_out = (const float*)d_in[3];
  const float* b_out = (const float*)d_in[4];
  float* out = (float*)d_out;

  ushort* xb    = (ushort*)d_ws;                    // 8192*1024
  ushort* wqkvb = xb    + (size_t)M_ * C_;          // 3072*1024
  ushort* woutb = wqkvb + (size_t)3 * C_ * C_;      // 1024*1024
  ushort* q     = woutb + (size_t)C_ * C_;          // [B,H,T,D] (exp2-domain scaled)
  ushort* kk    = q     + (size_t)M_ * C_;          // [B,H,T,D]
  ushort* vt    = kk    + (size_t)M_ * C_;          // [B,H,D,T]
  ushort* ao    = xb;                               // reuse xb (free after QKV GEMM)

  cvt_bf16<<<1024, 256, 0, stream>>>(x,     xb,    (M_ * C_) / 4);
  cvt_bf16<<<512,  256, 0, stream>>>(w_qkv, wqkvb, (3 * C_ * C_) / 4);
  cvt_bf16<<<256,  256, 0, stream>>>(w_out, woutb, (C_ * C_) / 4);

  gemm_bt<0><<<dim3(3 * C_ / 128, M_ / 128), 256, 0, stream>>>(
      xb, wqkvb, b_qkv, C_, q, kk, vt, nullptr);

  // 4 waves x (32 low + 32 high) rows = 256 rows per block -> 512 blocks.
  attn_k<<<B_ * H_ * T_ / 256, 256, 0, stream>>>(q, kk, vt, ao);

  gemm_bt<1><<<dim3(C_ / 128, M_ / 128), 256, 0, stream>>>(
      ao, woutb, b_out, C_, nullptr, nullptr, nullptr, out);
}

// Round 13
// 218.067 us; speedup vs baseline: 1.4759x; 1.0045x over previous
//
#include <hip/hip_runtime.h>
#include <hip/hip_bf16.h>

// CausalSelfAttention: x[4,2048,1024] -> qkv proj -> 16-head causal attn -> out proj
// Pipeline: cvt(fp32->bf16) x3 -> gemm_bt<QKV> (LDS granule-XOR swizzle) ->
// attn (32x32 MFMA, shfl pair-reduce softmax) -> gemm_bt<OUT>

#define B_ 4
#define T_ 2048
#define C_ 1024
#define H_ 16
#define D_ 64
#define M_ (B_*T_)   // 8192 tokens

#define SCALE_LOG2 0.18033688f   // (1/sqrt(64)) * log2(e), folded into Q in GEMM

typedef __attribute__((ext_vector_type(8))) short short8;
typedef __attribute__((ext_vector_type(4))) float f32x4;
typedef __attribute__((ext_vector_type(16))) float f32x16;

static __device__ __forceinline__ ushort f2bf(float f) {
  __hip_bfloat16 b = __float2bfloat16(f);
  ushort u; __builtin_memcpy(&u, &b, 2); return u;
}

static __device__ __forceinline__ void ld16(const void* g, void* l) {
  __builtin_amdgcn_global_load_lds((const __attribute__((address_space(1))) void*)g,
                                   (__attribute__((address_space(3))) void*)l, 16, 0, 0);
}

static __device__ __forceinline__ f32x4 mfma16(short8 a, short8 b, f32x4 c) {
  return __builtin_amdgcn_mfma_f32_16x16x32_bf16(a, b, c, 0, 0, 0);
}
static __device__ __forceinline__ f32x16 mfma32(short8 a, short8 b, f32x16 c) {
  return __builtin_amdgcn_mfma_f32_32x32x16_bf16(a, b, c, 0, 0, 0);
}

// Pair reduce across (lane, lane+32) via known-good shuffle.
static __device__ __forceinline__ float pair_max(float x) {
  return fmaxf(x, __shfl_xor(x, 32));
}
static __device__ __forceinline__ float pair_sum(float x) {
  return x + __shfl_xor(x, 32);
}

// ---------------- fp32 -> bf16 convert ----------------
__global__ void cvt_bf16(const float* __restrict__ in, ushort* __restrict__ out, int n4) {
  int i = blockIdx.x * blockDim.x + threadIdx.x;
  int st = gridDim.x * blockDim.x;
  for (; i < n4; i += st) {
    float4 v = ((const float4*)in)[i];
    ushort4 o;
    o.x = f2bf(v.x); o.y = f2bf(v.y); o.z = f2bf(v.z); o.w = f2bf(v.w);
    ((ushort4*)out)[i] = o;
  }
}

// ---------------- C = A @ B^T + bias (both A,B K-major bf16) ----------------
// LDS tiles [128 rows][4 granules of 16B]; 64B row stride alone is an 8-way
// bank conflict on ds_read_b128 (row covers half the banks, rows alternate
// halves). Fix: granule-XOR swizzle keyed on (row>>1)&3 — staging pre-XORs the
// GLOBAL source granule (LDS dest stays linear for global_load_lds), fragment
// reads apply the same XOR (involution).
// MODE 0: QKV projection -> scatter to q[B,H,T,D] (pre-scaled by SCALE_LOG2),
//         k[B,H,T,D], vt[B,H,D,T] (bf16)
// MODE 1: out projection -> fp32 d_out
template<int MODE>
__global__ __launch_bounds__(256) void gemm_bt(
    const ushort* __restrict__ A, const ushort* __restrict__ Bm,
    const float* __restrict__ bias, int K,
    ushort* __restrict__ q, ushort* __restrict__ kk, ushort* __restrict__ vt,
    float* __restrict__ outF)
{
  __shared__ ushort Al[128*32];
  __shared__ ushort Bl[128*32];
  const int tid = threadIdx.x;
  const int lane = tid & 63;
  const int w = tid >> 6;
  const int wr = w >> 1, wc = w & 1;
  const int l15 = lane & 15, lhi = lane >> 4;
  const long i0 = (long)blockIdx.y * 128;
  const long j0 = (long)blockIdx.x * 128;

  // swizzled granule index for fragment reads: lhi ^ ((row>>1)&3), and row
  // base (wr*64 + m*16) is a multiple of 16 -> reduces to lhi ^ ((l15>>1)&3).
  const int gsw = (lhi ^ ((l15 >> 1) & 3)) * 8;

  f32x4 acc[4][4] = {};

  for (int k0 = 0; k0 < K; k0 += 32) {
    __syncthreads();
    {
      int c = tid;
      int row = c >> 2, gs = (c & 3) ^ ((row >> 1) & 3);
      ld16((const char*)A  + ((i0 + row) * K + k0 + gs * 8) * 2, (char*)Al + c * 16);
      ld16((const char*)Bm + ((j0 + row) * K + k0 + gs * 8) * 2, (char*)Bl + c * 16);
      c = tid + 256;
      row = c >> 2; gs = (c & 3) ^ ((row >> 1) & 3);
      ld16((const char*)A  + ((i0 + row) * K + k0 + gs * 8) * 2, (char*)Al + c * 16);
      ld16((const char*)Bm + ((j0 + row) * K + k0 + gs * 8) * 2, (char*)Bl + c * 16);
    }
    __syncthreads();
    short8 af[4], bf[4];
#pragma unroll
    for (int m = 0; m < 4; m++) af[m] = *(const short8*)&Al[(wr*64 + m*16 + l15)*32 + gsw];
#pragma unroll
    for (int n = 0; n < 4; n++) bf[n] = *(const short8*)&Bl[(wc*64 + n*16 + l15)*32 + gsw];
#pragma unroll
    for (int m = 0; m < 4; m++)
#pragma unroll
      for (int n = 0; n < 4; n++)
        acc[m][n] = mfma16(af[m], bf[n], acc[m][n]);
  }

#pragma unroll
  for (int m = 0; m < 4; m++) {
#pragma unroll
    for (int n = 0; n < 4; n++) {
#pragma unroll
      for (int r = 0; r < 4; r++) {
        long i = i0 + wr*64 + m*16 + lhi*4 + r;       // token row
        int  j = (int)j0 + wc*64 + n*16 + l15;        // output feature
        float v = acc[m][n][r] + bias[j];
        if (MODE == 0) {
          int b = (int)(i >> 11), t = (int)(i & 2047);
          int sel = j >> 10, cc = j & 1023;
          int h = cc >> 6, d = cc & 63;
          long bh = (long)b * H_ + h;
          if (sel == 0)      q [(bh*T_ + t)*D_ + d] = f2bf(v * SCALE_LOG2);
          else if (sel == 1) kk[(bh*T_ + t)*D_ + d] = f2bf(v);
          else               vt[(bh*D_ + d)*T_ + t] = f2bf(v);  // V transposed
        } else {
          outF[i * C_ + j] = v;
        }
      }
    }
  }
}

// ------------- causal flash attention, 32x32 MFMA, LDS-P relayout -------------
// 512 blocks x 256 threads (4 waves). head = bb&63 (8 heads/XCD), i = bb>>6,
// J = i<4 ? i : 11-i (co-resident bb, bb+256 sum to constant work).
// Wave w: low rows [128J+32w, +31], high rows mirror. KVBLK=64 staged
// double-buffered (counted vmcnt, XOR granule swizzle).
// QK^T = mfma32(K, Q): lane(q=l31,hi) holds S[kv=(r&3)+8(r>>2)+4hi+32c][q].
// Softmax in-register: exact row max (shfl pair reduce), unconditional
// rescale, lane-partial l. P -> bf16 pairs -> wave-private LDS (stride 20
// u32/row) -> uint4 B-fragment reads. PV = mfma32(Vt, P) -> O'[d][q].
#define PSTR 20   // u32 per q-row: 16 pairs + 4 pad

static __device__ __forceinline__ void softmax_pack32(
    f32x16& sc, float& m, float& lp, f32x16 (&o)[2],
    int q0, int kvbase, int l31, int hi, uint* __restrict__ P)
{
  float sv[16];
  const bool needmask = (kvbase + 31 > q0);
#pragma unroll
  for (int r = 0; r < 16; r++) {
    float xv = sc[r];
    if (needmask) {
      int kv = kvbase + (r & 3) + 8 * (r >> 2) + 4 * hi;
      if (kv > q0 + l31) xv = -1e30f;
    }
    sv[r] = xv;
  }
  // exact row max: in-lane tree + pair reduce
  float p0 = fmaxf(fmaxf(sv[0], sv[1]),  fmaxf(sv[2], sv[3]));
  float p1 = fmaxf(fmaxf(sv[4], sv[5]),  fmaxf(sv[6], sv[7]));
  float p2 = fmaxf(fmaxf(sv[8], sv[9]),  fmaxf(sv[10], sv[11]));
  float p3 = fmaxf(fmaxf(sv[12], sv[13]), fmaxf(sv[14], sv[15]));
  float pm = fmaxf(fmaxf(p0, p1), fmaxf(p2, p3));
  float rowm = pair_max(pm);
  // unconditional rescale
  float nm = fmaxf(m, rowm);
  float alpha = __builtin_amdgcn_exp2f(m - nm);
  m = nm;
  lp *= alpha;
#pragma unroll
  for (int dt = 0; dt < 2; dt++)
#pragma unroll
    for (int r = 0; r < 16; r++) o[dt][r] *= alpha;
  float s = 0.f;
#pragma unroll
  for (int r = 0; r < 16; r++) {
    float p = __builtin_amdgcn_exp2f(sv[r] - m);
    sv[r] = p;
    s += p;
  }
  lp += s;
  // pack pairs (kv 2j, 2j+1) and store: W[j] -> pair pos 4*(j>>1)+(j&1)+2hi
  uint W[8];
#pragma unroll
  for (int r = 0; r < 8; r++)
    asm("v_cvt_pk_bf16_f32 %0, %1, %2" : "=v"(W[r]) : "v"(sv[2*r]), "v"(sv[2*r+1]));
#pragma unroll
  for (int r2 = 0; r2 < 4; r2++) {
    uint2 pr; pr.x = W[2*r2]; pr.y = W[2*r2 + 1];
    *(uint2*)&P[l31 * PSTR + r2*4 + 2*hi] = pr;
  }
}

__global__ __launch_bounds__(256, 2) void attn_k(
    const ushort* __restrict__ Q, const ushort* __restrict__ K,
    const ushort* __restrict__ V, ushort* __restrict__ AO)
{
  __shared__ ushort Kt[2][64*64];
  __shared__ ushort Vt[2][64*64];
  __shared__ uint P2[8][32 * PSTR];    // [wave*2 + group][q-row][pair]
  const int tid = threadIdx.x;
  const int lane = tid & 63;
  const int w = tid >> 6;              // 0..3
  const int l31 = lane & 31, hi = lane >> 5;
  const int bb = blockIdx.x;
  const int head = bb & 63;
  const int i = bb >> 6;               // 0..7
  const int J = (i < 4) ? i : 11 - i;
  const int nst = 32 - 2 * J;          // kv steps (>= 18)
  const int q0a = 128 * J + 32 * w;            // low band
  const int q0b = 2016 - 128 * J - 32 * w;     // high (mirror) band

  const ushort* Qb = Q + (size_t)head * T_ * D_;
  const ushort* Kb = K + (size_t)head * T_ * D_;
  const ushort* Vb = V + (size_t)head * D_ * T_;   // [d][t]

  auto STAGE = [&](int buf, int kv0s) {
#pragma unroll
    for (int hb = 0; hb < 2; hb++) {
      int slot = tid + hb * 256;            // 0..511
      int row = slot >> 3, g = slot & 7, gs = g ^ (row & 7);
      ld16((const char*)Kb + ((size_t)(kv0s + row) * D_ + gs * 8) * 2,
           (char*)&Kt[buf][0] + slot * 16);
      ld16((const char*)Vb + ((size_t)row * T_ + kv0s + gs * 8) * 2,
           (char*)&Vt[buf][0] + slot * 16);
    }
  };

  // Q as B-fragment: lane holds Q[q0+l31][d = s*16 + hi*8 + e] per slice s.
  short8 qfa[4], qfb[4];
#pragma unroll
  for (int s = 0; s < 4; s++) {
    qfa[s] = *(const short8*)&Qb[(q0a + l31) * D_ + s*16 + hi*8];
    qfb[s] = *(const short8*)&Qb[(q0b + l31) * D_ + s*16 + hi*8];
  }

  f32x16 oa[2] = {}, ob[2] = {};       // O'[d][q]: d = dt*32 + (r&3)+8(r>>2)+4hi
  float ma = -1e30f, la = 0.f, mb = -1e30f, lb = 0.f;

  STAGE(0, 0);
  STAGE(1, 64);
  int cur = 0;

  for (int t = 0; t < nst; t++) {
    const int kv0 = t * 64;
    if (t + 1 < nst) { asm volatile("s_waitcnt vmcnt(4)" ::: "memory"); }
    else             { asm volatile("s_waitcnt vmcnt(0)" ::: "memory"); }
    __builtin_amdgcn_s_barrier();
    __builtin_amdgcn_sched_barrier(0);

#pragma unroll
    for (int c = 0; c < 2; c++) {
      const int kvc = kv0 + 32 * c;
      const bool act_b = (kvc <= q0b + 31);
      const bool act_a = (kvc <= q0a + 31);   // act_a implies act_b
      if (act_b) {
        // K A-fragment: lane holds K[c*32+l31][d = s*16 + hi*8 + e]
        short8 kf[4];
#pragma unroll
        for (int s = 0; s < 4; s++) {
          const int row = c*32 + l31;
          kf[s] = *(const short8*)&Kt[cur][row*64 + (((2*s + hi) ^ (row & 7)) << 3)];
        }
        f32x16 scb = {}, sca = {};
        __builtin_amdgcn_s_setprio(1);
#pragma unroll
        for (int s = 0; s < 4; s++) scb = mfma32(kf[s], qfb[s], scb);
        if (act_a) {
#pragma unroll
          for (int s = 0; s < 4; s++) sca = mfma32(kf[s], qfa[s], sca);
        }
        __builtin_amdgcn_s_setprio(0);

        // Vt A-fragment for slices sl=0,1: Vt[dt*32+l31][kv = c*32+sl*16+hi*8+e]
        short8 vf[2][2];
#pragma unroll
        for (int sl = 0; sl < 2; sl++)
#pragma unroll
          for (int dt = 0; dt < 2; dt++) {
            const int row = dt*32 + l31;
            vf[sl][dt] = *(const short8*)
                &Vt[cur][row*64 + (((2*(2*c + sl) + hi) ^ (row & 7)) << 3)];
          }

        softmax_pack32(scb, mb, lb, ob, q0b, kvc, l31, hi, &P2[w*2][0]);
        if (act_a) softmax_pack32(sca, ma, la, oa, q0a, kvc, l31, hi, &P2[w*2+1][0]);

        asm volatile("s_waitcnt lgkmcnt(0)" ::: "memory");
        __builtin_amdgcn_sched_barrier(0);
        // B-fragment read: lane (l31,hi) needs pairs sl*8 + hi*4 + {0..3}
        short8 pfb[2], pfa[2];
#pragma unroll
        for (int sl = 0; sl < 2; sl++) {
          uint4 pw = *(const uint4*)&P2[w*2][l31 * PSTR + sl*8 + hi*4];
          __builtin_memcpy(&pfb[sl], &pw, 16);
        }
        if (act_a) {
#pragma unroll
          for (int sl = 0; sl < 2; sl++) {
            uint4 pw = *(const uint4*)&P2[w*2+1][l31 * PSTR + sl*8 + hi*4];
            __builtin_memcpy(&pfa[sl], &pw, 16);
          }
        }
        __builtin_amdgcn_s_setprio(1);
#pragma unroll
        for (int sl = 0; sl < 2; sl++)
#pragma unroll
          for (int dt = 0; dt < 2; dt++)
            ob[dt] = mfma32(vf[sl][dt], pfb[sl], ob[dt]);
        if (act_a) {
#pragma unroll
          for (int sl = 0; sl < 2; sl++)
#pragma unroll
            for (int dt = 0; dt < 2; dt++)
              oa[dt] = mfma32(vf[sl][dt], pfa[sl], oa[dt]);
        }
        __builtin_amdgcn_s_setprio(0);
      }
    }

    __builtin_amdgcn_s_barrier();
    __builtin_amdgcn_sched_barrier(0);
    if (t + 2 < nst) STAGE(cur, kv0 + 128);   // overwrite freed buffer
    cur ^= 1;
  }

  const int b = head >> 4, h = head & 15;
  {
    const float invl = 1.0f / pair_sum(lb);
    const size_t rowb = (size_t)(b * T_ + q0b + l31) * C_ + h * 64;
#pragma unroll
    for (int dt = 0; dt < 2; dt++)
#pragma unroll
      for (int rg = 0; rg < 4; rg++) {
        const int d0 = dt*32 + 8*rg + 4*hi;
        ushort4 ov;
        ov.x = f2bf(ob[dt][rg*4+0] * invl);
        ov.y = f2bf(ob[dt][rg*4+1] * invl);
        ov.z = f2bf(ob[dt][rg*4+2] * invl);
        ov.w = f2bf(ob[dt][rg*4+3] * invl);
        *(ushort4*)&AO[rowb + d0] = ov;
      }
  }
  {
    const float invl = 1.0f / pair_sum(la);
    const size_t rowb = (size_t)(b * T_ + q0a + l31) * C_ + h * 64;
#pragma unroll
    for (int dt = 0; dt < 2; dt++)
#pragma unroll
      for (int rg = 0; rg < 4; rg++) {
        const int d0 = dt*32 + 8*rg + 4*hi;
        ushort4 ov;
        ov.x = f2bf(oa[dt][rg*4+0] * invl);
        ov.y = f2bf(oa[dt][rg*4+1] * invl);
        ov.z = f2bf(oa[dt][rg*4+2] * invl);
        ov.w = f2bf(oa[dt][rg*4+3] * invl);
        *(ushort4*)&AO[rowb + d0] = ov;
      }
  }
}

extern "C" void kernel_launch(void* const* d_in, const int* in_sizes, int n_in,
                              void* d_out, int out_size, void* d_ws, size_t ws_size,
                              hipStream_t stream) {
  const float* x     = (const float*)d_in[0];
  const float* w_qkv = (const float*)d_in[1];
  const float* b_qkv = (const float*)d_in[2];
  const float* w_out = (const float*)d_in[3];
  const float* b_out = (const float*)d_in[4];
  float* out = (float*)d_out;

  ushort* xb    = (ushort*)d_ws;                    // 8192*1024
  ushort* wqkvb = xb    + (size_t)M_ * C_;          // 3072*1024
  ushort* woutb = wqkvb + (size_t)3 * C_ * C_;      // 1024*1024
  ushort* q     = woutb + (size_t)C_ * C_;          // [B,H,T,D] (exp2-domain scaled)
  ushort* kk    = q     + (size_t)M_ * C_;          // [B,H,T,D]
  ushort* vt    = kk    + (size_t)M_ * C_;          // [B,H,D,T]
  ushort* ao    = xb;                               // reuse xb (free after QKV GEMM)

  cvt_bf16<<<1024, 256, 0, stream>>>(x,     xb,    (M_ * C_) / 4);
  cvt_bf16<<<512,  256, 0, stream>>>(w_qkv, wqkvb, (3 * C_ * C_) / 4);
  cvt_bf16<<<256,  256, 0, stream>>>(w_out, woutb, (C_ * C_) / 4);

  gemm_bt<0><<<dim3(3 * C_ / 128, M_ / 128), 256, 0, stream>>>(
      xb, wqkvb, b_qkv, C_, q, kk, vt, nullptr);

  // 4 waves x (32 low + 32 high) rows = 256 rows per block -> 512 blocks.
  attn_k<<<B_ * H_ * T_ / 256, 256, 0, stream>>>(q, kk, vt, ao);

  gemm_bt<1><<<dim3(C_ / 128, M_ / 128), 256, 0, stream>>>(
      ao, woutb, b_out, C_, nullptr, nullptr, nullptr, out);
}

// Round 14
// 206.506 us; speedup vs baseline: 1.5586x; 1.0560x over previous
//
#include <hip/hip_runtime.h>
#include <hip/hip_bf16.h>

// CausalSelfAttention: x[4,2048,1024] -> qkv proj -> 16-head causal attn -> out proj
// Pipeline: cvt(fp32->bf16) x3 -> gemm_bt (counted-vmcnt dbuf, XOR swizzle) ->
// attn (KVBLK=128, 32x32 MFMA, sequential-band softmax) -> gemm_bt<OUT>

#define B_ 4
#define T_ 2048
#define C_ 1024
#define H_ 16
#define D_ 64
#define M_ (B_*T_)   // 8192 tokens

#define SCALE_LOG2 0.18033688f   // (1/sqrt(64)) * log2(e), folded into Q in GEMM

typedef __attribute__((ext_vector_type(8))) short short8;
typedef __attribute__((ext_vector_type(4))) float f32x4;
typedef __attribute__((ext_vector_type(16))) float f32x16;

static __device__ __forceinline__ ushort f2bf(float f) {
  __hip_bfloat16 b = __float2bfloat16(f);
  ushort u; __builtin_memcpy(&u, &b, 2); return u;
}

static __device__ __forceinline__ void ld16(const void* g, void* l) {
  __builtin_amdgcn_global_load_lds((const __attribute__((address_space(1))) void*)g,
                                   (__attribute__((address_space(3))) void*)l, 16, 0, 0);
}

static __device__ __forceinline__ f32x4 mfma16(short8 a, short8 b, f32x4 c) {
  return __builtin_amdgcn_mfma_f32_16x16x32_bf16(a, b, c, 0, 0, 0);
}
static __device__ __forceinline__ f32x16 mfma32(short8 a, short8 b, f32x16 c) {
  return __builtin_amdgcn_mfma_f32_32x32x16_bf16(a, b, c, 0, 0, 0);
}

// Pair reduce across (lane, lane+32) via known-good shuffle.
static __device__ __forceinline__ float pair_max(float x) {
  return fmaxf(x, __shfl_xor(x, 32));
}
static __device__ __forceinline__ float pair_sum(float x) {
  return x + __shfl_xor(x, 32);
}

// ---------------- fp32 -> bf16 convert ----------------
__global__ void cvt_bf16(const float* __restrict__ in, ushort* __restrict__ out, int n4) {
  int i = blockIdx.x * blockDim.x + threadIdx.x;
  int st = gridDim.x * blockDim.x;
  for (; i < n4; i += st) {
    float4 v = ((const float4*)in)[i];
    ushort4 o;
    o.x = f2bf(v.x); o.y = f2bf(v.y); o.z = f2bf(v.z); o.w = f2bf(v.w);
    ((ushort4*)out)[i] = o;
  }
}

// ---------------- C = A @ B^T + bias (both A,B K-major bf16) ----------------
// Double-buffered LDS + counted-vmcnt pipeline: per K-step
//   {vmcnt(4); s_barrier; ds_read+MFMA; s_barrier; STAGE(t+2 into freed buf)}
// — next tile's 4 global_load_lds stay in flight across barriers (no drain).
// Granule-XOR swizzle (r13-verified, conflicts=0): source granule pre-XORed
// by ((row>>1)&3); fragment reads apply the same XOR.
// MODE 0: QKV -> q[B,H,T,D] (pre-scaled), k[B,H,T,D], vt[B,H,D,T] (bf16)
// MODE 1: out projection -> fp32 d_out
template<int MODE>
__global__ __launch_bounds__(256) void gemm_bt(
    const ushort* __restrict__ A, const ushort* __restrict__ Bm,
    const float* __restrict__ bias, int K,
    ushort* __restrict__ q, ushort* __restrict__ kk, ushort* __restrict__ vt,
    float* __restrict__ outF)
{
  __shared__ ushort Al[2][128*32];
  __shared__ ushort Bl[2][128*32];
  const int tid = threadIdx.x;
  const int lane = tid & 63;
  const int w = tid >> 6;
  const int wr = w >> 1, wc = w & 1;
  const int l15 = lane & 15, lhi = lane >> 4;
  const long i0 = (long)blockIdx.y * 128;
  const long j0 = (long)blockIdx.x * 128;

  const int gsw = (lhi ^ ((l15 >> 1) & 3)) * 8;

  auto STAGE = [&](int buf, int k0) {
    int c = tid;
    int row = c >> 2, gs = (c & 3) ^ ((row >> 1) & 3);
    ld16((const char*)A  + ((i0 + row) * K + k0 + gs * 8) * 2, (char*)&Al[buf][0] + c * 16);
    ld16((const char*)Bm + ((j0 + row) * K + k0 + gs * 8) * 2, (char*)&Bl[buf][0] + c * 16);
    c = tid + 256;
    row = c >> 2; gs = (c & 3) ^ ((row >> 1) & 3);
    ld16((const char*)A  + ((i0 + row) * K + k0 + gs * 8) * 2, (char*)&Al[buf][0] + c * 16);
    ld16((const char*)Bm + ((j0 + row) * K + k0 + gs * 8) * 2, (char*)&Bl[buf][0] + c * 16);
  };

  f32x4 acc[4][4] = {};
  const int nsteps = K >> 5;

  STAGE(0, 0);
  STAGE(1, 32);
  int cur = 0;

  for (int t = 0; t < nsteps; t++) {
    if (t + 1 < nsteps) { asm volatile("s_waitcnt vmcnt(4)" ::: "memory"); }
    else                { asm volatile("s_waitcnt vmcnt(0)" ::: "memory"); }
    __builtin_amdgcn_s_barrier();
    __builtin_amdgcn_sched_barrier(0);

    short8 af[4], bf[4];
#pragma unroll
    for (int m = 0; m < 4; m++) af[m] = *(const short8*)&Al[cur][(wr*64 + m*16 + l15)*32 + gsw];
#pragma unroll
    for (int n = 0; n < 4; n++) bf[n] = *(const short8*)&Bl[cur][(wc*64 + n*16 + l15)*32 + gsw];
    __builtin_amdgcn_s_setprio(1);
#pragma unroll
    for (int m = 0; m < 4; m++)
#pragma unroll
      for (int n = 0; n < 4; n++)
        acc[m][n] = mfma16(af[m], bf[n], acc[m][n]);
    __builtin_amdgcn_s_setprio(0);

    __builtin_amdgcn_s_barrier();          // all waves done reading buf[cur]
    __builtin_amdgcn_sched_barrier(0);
    if (t + 2 < nsteps) STAGE(cur, (t + 2) * 32);
    cur ^= 1;
  }

#pragma unroll
  for (int m = 0; m < 4; m++) {
#pragma unroll
    for (int n = 0; n < 4; n++) {
#pragma unroll
      for (int r = 0; r < 4; r++) {
        long i = i0 + wr*64 + m*16 + lhi*4 + r;       // token row
        int  j = (int)j0 + wc*64 + n*16 + l15;        // output feature
        float v = acc[m][n][r] + bias[j];
        if (MODE == 0) {
          int b = (int)(i >> 11), t = (int)(i & 2047);
          int sel = j >> 10, cc = j & 1023;
          int h = cc >> 6, d = cc & 63;
          long bh = (long)b * H_ + h;
          if (sel == 0)      q [(bh*T_ + t)*D_ + d] = f2bf(v * SCALE_LOG2);
          else if (sel == 1) kk[(bh*T_ + t)*D_ + d] = f2bf(v);
          else               vt[(bh*D_ + d)*T_ + t] = f2bf(v);  // V transposed
        } else {
          outF[i * C_ + j] = v;
        }
      }
    }
  }
}

// ------------- causal flash attention, KVBLK=128, 32x32 MFMA -------------
// 512 blocks x 256 threads (4 waves). head = bb&63 (8 heads/XCD), i = bb>>6,
// J = i<4 ? i : 11-i. Wave w: low rows [128J+32w,+31], high rows mirror.
// K[128][64] + Vt[64][128] double-buffered (counted vmcnt(8), XOR granule
// swizzle: K g^(row&7), V g^(row&15)). Per 32-kv chunk: QK=mfma32(K,Q),
// softmax in-register (exact row max via shfl pair-reduce, lane-partial l),
// bands processed SEQUENTIALLY sharing one wave-private P buffer (10KB P2).
// PV = mfma32(Vt, P). LDS total 74KB -> 2 blocks/CU.
#define PSTR 20   // u32 per q-row: 16 pairs + 4 pad

static __device__ __forceinline__ void softmax_pack32(
    f32x16& sc, float& m, float& lp, f32x16 (&o)[2],
    int q0, int kvbase, int l31, int hi, uint* __restrict__ P)
{
  float sv[16];
  const bool needmask = (kvbase + 31 > q0);
#pragma unroll
  for (int r = 0; r < 16; r++) {
    float xv = sc[r];
    if (needmask) {
      int kv = kvbase + (r & 3) + 8 * (r >> 2) + 4 * hi;
      if (kv > q0 + l31) xv = -1e30f;
    }
    sv[r] = xv;
  }
  float p0 = fmaxf(fmaxf(sv[0], sv[1]),  fmaxf(sv[2], sv[3]));
  float p1 = fmaxf(fmaxf(sv[4], sv[5]),  fmaxf(sv[6], sv[7]));
  float p2 = fmaxf(fmaxf(sv[8], sv[9]),  fmaxf(sv[10], sv[11]));
  float p3 = fmaxf(fmaxf(sv[12], sv[13]), fmaxf(sv[14], sv[15]));
  float pm = fmaxf(fmaxf(p0, p1), fmaxf(p2, p3));
  float rowm = pair_max(pm);
  float nm = fmaxf(m, rowm);
  float alpha = __builtin_amdgcn_exp2f(m - nm);
  m = nm;
  lp *= alpha;
#pragma unroll
  for (int dt = 0; dt < 2; dt++)
#pragma unroll
    for (int r = 0; r < 16; r++) o[dt][r] *= alpha;
  float s = 0.f;
#pragma unroll
  for (int r = 0; r < 16; r++) {
    float p = __builtin_amdgcn_exp2f(sv[r] - m);
    sv[r] = p;
    s += p;
  }
  lp += s;
  uint W[8];
#pragma unroll
  for (int r = 0; r < 8; r++)
    asm("v_cvt_pk_bf16_f32 %0, %1, %2" : "=v"(W[r]) : "v"(sv[2*r]), "v"(sv[2*r+1]));
#pragma unroll
  for (int r2 = 0; r2 < 4; r2++) {
    uint2 pr; pr.x = W[2*r2]; pr.y = W[2*r2 + 1];
    *(uint2*)&P[l31 * PSTR + r2*4 + 2*hi] = pr;
  }
}

__global__ __launch_bounds__(256, 2) void attn_k(
    const ushort* __restrict__ Q, const ushort* __restrict__ K,
    const ushort* __restrict__ V, ushort* __restrict__ AO)
{
  __shared__ ushort Kt[2][128*64];
  __shared__ ushort Vt[2][64*128];
  __shared__ uint P2[4][32 * PSTR];    // one buffer per wave (bands sequential)
  const int tid = threadIdx.x;
  const int lane = tid & 63;
  const int w = tid >> 6;              // 0..3
  const int l31 = lane & 31, hi = lane >> 5;
  const int bb = blockIdx.x;
  const int head = bb & 63;
  const int i = bb >> 6;               // 0..7
  const int J = (i < 4) ? i : 11 - i;
  const int nst = 16 - J;              // 128-kv tiles (>= 13)
  const int q0a = 128 * J + 32 * w;            // low band
  const int q0b = 2016 - 128 * J - 32 * w;     // high (mirror) band

  const ushort* Qb = Q + (size_t)head * T_ * D_;
  const ushort* Kb = K + (size_t)head * T_ * D_;
  const ushort* Vb = V + (size_t)head * D_ * T_;   // [d][t]

  // Stage K[128][64] (8 granules/row, g^(row&7)) and Vt[64][128] (16
  // granules/row, g^(row&15)); linear LDS dest, pre-swizzled global source.
  auto STAGE = [&](int buf, int kv0s) {
#pragma unroll
    for (int hb = 0; hb < 4; hb++) {
      int slot = tid + hb * 256;            // 0..1023
      int krow = slot >> 3, kg = slot & 7, kgs = kg ^ (krow & 7);
      ld16((const char*)Kb + ((size_t)(kv0s + krow) * D_ + kgs * 8) * 2,
           (char*)&Kt[buf][0] + slot * 16);
      int vrow = slot >> 4, vg = slot & 15, vgs = vg ^ (vrow & 15);
      ld16((const char*)Vb + ((size_t)vrow * T_ + kv0s + vgs * 8) * 2,
           (char*)&Vt[buf][0] + slot * 16);
    }
  };

  // Q as B-fragment: lane holds Q[q0+l31][d = s*16 + hi*8 + e] per slice s.
  short8 qfa[4], qfb[4];
#pragma unroll
  for (int s = 0; s < 4; s++) {
    qfa[s] = *(const short8*)&Qb[(q0a + l31) * D_ + s*16 + hi*8];
    qfb[s] = *(const short8*)&Qb[(q0b + l31) * D_ + s*16 + hi*8];
  }

  f32x16 oa[2] = {}, ob[2] = {};       // O'[d][q]: d = dt*32 + (r&3)+8(r>>2)+4hi
  float ma = -1e30f, la = 0.f, mb = -1e30f, lb = 0.f;

  STAGE(0, 0);
  STAGE(1, 128);
  int cur = 0;
  uint* P = &P2[w][0];

  for (int t = 0; t < nst; t++) {
    const int kv0 = t * 128;
    if (t + 1 < nst) { asm volatile("s_waitcnt vmcnt(8)" ::: "memory"); }
    else             { asm volatile("s_waitcnt vmcnt(0)" ::: "memory"); }
    __builtin_amdgcn_s_barrier();
    __builtin_amdgcn_sched_barrier(0);

#pragma unroll
    for (int c = 0; c < 4; c++) {
      const int kvc = kv0 + 32 * c;
      const bool act_b = (kvc <= q0b + 31);
      const bool act_a = (kvc <= q0a + 31);   // act_a implies act_b
      if (act_b) {
        // K A-fragment: lane holds K[c*32+l31][d = s*16 + hi*8 + e]
        short8 kf[4];
#pragma unroll
        for (int s = 0; s < 4; s++) {
          const int row = c*32 + l31;
          kf[s] = *(const short8*)&Kt[cur][row*64 + (((2*s + hi) ^ (row & 7)) << 3)];
        }
        // Vt A-fragment: Vt[dt*32+l31][kv = c*32 + sl*16 + hi*8 + e]
        short8 vf[2][2];
#pragma unroll
        for (int sl = 0; sl < 2; sl++)
#pragma unroll
          for (int dt = 0; dt < 2; dt++) {
            const int row = dt*32 + l31;
            const int u = c*4 + sl*2 + hi;
            vf[sl][dt] = *(const short8*)
                &Vt[cur][row*128 + ((u ^ (row & 15)) << 3)];
          }

        // ---- band b ----
        {
          f32x16 scb = {};
          __builtin_amdgcn_s_setprio(1);
#pragma unroll
          for (int s = 0; s < 4; s++) scb = mfma32(kf[s], qfb[s], scb);
          __builtin_amdgcn_s_setprio(0);
          softmax_pack32(scb, mb, lb, ob, q0b, kvc, l31, hi, P);
          asm volatile("s_waitcnt lgkmcnt(0)" ::: "memory");
          __builtin_amdgcn_sched_barrier(0);
          short8 pf[2];
#pragma unroll
          for (int sl = 0; sl < 2; sl++) {
            uint4 pw = *(const uint4*)&P[l31 * PSTR + sl*8 + hi*4];
            __builtin_memcpy(&pf[sl], &pw, 16);
          }
          __builtin_amdgcn_s_setprio(1);
#pragma unroll
          for (int sl = 0; sl < 2; sl++)
#pragma unroll
            for (int dt = 0; dt < 2; dt++)
              ob[dt] = mfma32(vf[sl][dt], pf[sl], ob[dt]);
          __builtin_amdgcn_s_setprio(0);
          __builtin_amdgcn_sched_barrier(0);
        }
        // ---- band a (reuses kf, vf, P buffer) ----
        if (act_a) {
          f32x16 sca = {};
          __builtin_amdgcn_s_setprio(1);
#pragma unroll
          for (int s = 0; s < 4; s++) sca = mfma32(kf[s], qfa[s], sca);
          __builtin_amdgcn_s_setprio(0);
          softmax_pack32(sca, ma, la, oa, q0a, kvc, l31, hi, P);
          asm volatile("s_waitcnt lgkmcnt(0)" ::: "memory");
          __builtin_amdgcn_sched_barrier(0);
          short8 pf[2];
#pragma unroll
          for (int sl = 0; sl < 2; sl++) {
            uint4 pw = *(const uint4*)&P[l31 * PSTR + sl*8 + hi*4];
            __builtin_memcpy(&pf[sl], &pw, 16);
          }
          __builtin_amdgcn_s_setprio(1);
#pragma unroll
          for (int sl = 0; sl < 2; sl++)
#pragma unroll
            for (int dt = 0; dt < 2; dt++)
              oa[dt] = mfma32(vf[sl][dt], pf[sl], oa[dt]);
          __builtin_amdgcn_s_setprio(0);
          __builtin_amdgcn_sched_barrier(0);
        }
      }
    }

    __builtin_amdgcn_s_barrier();
    __builtin_amdgcn_sched_barrier(0);
    if (t + 2 < nst) STAGE(cur, kv0 + 256);   // overwrite freed buffer
    cur ^= 1;
  }

  const int b = head >> 4, h = head & 15;
  {
    const float invl = 1.0f / pair_sum(lb);
    const size_t rowb = (size_t)(b * T_ + q0b + l31) * C_ + h * 64;
#pragma unroll
    for (int dt = 0; dt < 2; dt++)
#pragma unroll
      for (int rg = 0; rg < 4; rg++) {
        const int d0 = dt*32 + 8*rg + 4*hi;
        ushort4 ov;
        ov.x = f2bf(ob[dt][rg*4+0] * invl);
        ov.y = f2bf(ob[dt][rg*4+1] * invl);
        ov.z = f2bf(ob[dt][rg*4+2] * invl);
        ov.w = f2bf(ob[dt][rg*4+3] * invl);
        *(ushort4*)&AO[rowb + d0] = ov;
      }
  }
  {
    const float invl = 1.0f / pair_sum(la);
    const size_t rowb = (size_t)(b * T_ + q0a + l31) * C_ + h * 64;
#pragma unroll
    for (int dt = 0; dt < 2; dt++)
#pragma unroll
      for (int rg = 0; rg < 4; rg++) {
        const int d0 = dt*32 + 8*rg + 4*hi;
        ushort4 ov;
        ov.x = f2bf(oa[dt][rg*4+0] * invl);
        ov.y = f2bf(oa[dt][rg*4+1] * invl);
        ov.z = f2bf(oa[dt][rg*4+2] * invl);
        ov.w = f2bf(oa[dt][rg*4+3] * invl);
        *(ushort4*)&AO[rowb + d0] = ov;
      }
  }
}

extern "C" void kernel_launch(void* const* d_in, const int* in_sizes, int n_in,
                              void* d_out, int out_size, void* d_ws, size_t ws_size,
                              hipStream_t stream) {
  const float* x     = (const float*)d_in[0];
  const float* w_qkv = (const float*)d_in[1];
  const float* b_qkv = (const float*)d_in[2];
  const float* w_out = (const float*)d_in[3];
  const float* b_out = (const float*)d_in[4];
  float* out = (float*)d_out;

  ushort* xb    = (ushort*)d_ws;                    // 8192*1024
  ushort* wqkvb = xb    + (size_t)M_ * C_;          // 3072*1024
  ushort* woutb = wqkvb + (size_t)3 * C_ * C_;      // 1024*1024
  ushort* q     = woutb + (size_t)C_ * C_;          // [B,H,T,D] (exp2-domain scaled)
  ushort* kk    = q     + (size_t)M_ * C_;          // [B,H,T,D]
  ushort* vt    = kk    + (size_t)M_ * C_;          // [B,H,D,T]
  ushort* ao    = xb;                               // reuse xb (free after QKV GEMM)

  cvt_bf16<<<1024, 256, 0, stream>>>(x,     xb,    (M_ * C_) / 4);
  cvt_bf16<<<512,  256, 0, stream>>>(w_qkv, wqkvb, (3 * C_ * C_) / 4);
  cvt_bf16<<<256,  256, 0, stream>>>(w_out, woutb, (C_ * C_) / 4);

  gemm_bt<0><<<dim3(3 * C_ / 128, M_ / 128), 256, 0, stream>>>(
      xb, wqkvb, b_qkv, C_, q, kk, vt, nullptr);

  // 4 waves x (32 low + 32 high) rows = 256 rows per block -> 512 blocks.
  attn_k<<<B_ * H_ * T_ / 256, 256, 0, stream>>>(q, kk, vt, ao);

  gemm_bt<1><<<dim3(C_ / 128, M_ / 128), 256, 0, stream>>>(
      ao, woutb, b_out, C_, nullptr, nullptr, nullptr, out);
}

// Round 15
// 184.596 us; speedup vs baseline: 1.7435x; 1.1187x over previous
//
#include <hip/hip_runtime.h>
#include <hip/hip_bf16.h>

// CausalSelfAttention: x[4,2048,1024] -> qkv proj -> 16-head causal attn -> out proj
// Pipeline: cvt3 -> gemm_bt<QKV> (counted vmcnt, XOR swizzle, LDS-transposed
// V epilogue) -> attn (single-band blocks, longest-first backfill) -> gemm_bt<OUT>

#define B_ 4
#define T_ 2048
#define C_ 1024
#define H_ 16
#define D_ 64
#define M_ (B_*T_)   // 8192 tokens

#define SCALE_LOG2 0.18033688f   // (1/sqrt(64)) * log2(e), folded into Q in GEMM

typedef __attribute__((ext_vector_type(8))) short short8;
typedef __attribute__((ext_vector_type(4))) float f32x4;
typedef __attribute__((ext_vector_type(16))) float f32x16;

static __device__ __forceinline__ ushort f2bf(float f) {
  __hip_bfloat16 b = __float2bfloat16(f);
  ushort u; __builtin_memcpy(&u, &b, 2); return u;
}

static __device__ __forceinline__ void ld16(const void* g, void* l) {
  __builtin_amdgcn_global_load_lds((const __attribute__((address_space(1))) void*)g,
                                   (__attribute__((address_space(3))) void*)l, 16, 0, 0);
}

static __device__ __forceinline__ f32x4 mfma16(short8 a, short8 b, f32x4 c) {
  return __builtin_amdgcn_mfma_f32_16x16x32_bf16(a, b, c, 0, 0, 0);
}
static __device__ __forceinline__ f32x16 mfma32(short8 a, short8 b, f32x16 c) {
  return __builtin_amdgcn_mfma_f32_32x32x16_bf16(a, b, c, 0, 0, 0);
}

static __device__ __forceinline__ float pair_max(float x) {
  return fmaxf(x, __shfl_xor(x, 32));
}
static __device__ __forceinline__ float pair_sum(float x) {
  return x + __shfl_xor(x, 32);
}

// ---------------- fp32 -> bf16 convert, all three tensors in one launch ----
__global__ void cvt3(const float* __restrict__ a, const float* __restrict__ b,
                     const float* __restrict__ c, ushort* __restrict__ oa,
                     ushort* __restrict__ ob, ushort* __restrict__ oc,
                     int na, int nb, int nc) {
  int tot = na + nb + nc;
  int i = blockIdx.x * blockDim.x + threadIdx.x;
  int st = gridDim.x * blockDim.x;
  for (; i < tot; i += st) {
    const float* s; ushort* d; int k = i;
    if (k < na)            { s = a; d = oa; }
    else if (k < na + nb)  { k -= na; s = b; d = ob; }
    else                   { k -= na + nb; s = c; d = oc; }
    float4 v = ((const float4*)s)[k];
    ushort4 o;
    o.x = f2bf(v.x); o.y = f2bf(v.y); o.z = f2bf(v.z); o.w = f2bf(v.w);
    ((ushort4*)d)[k] = o;
  }
}

// ---------------- C = A @ B^T + bias (both A,B K-major bf16) ----------------
// Counted-vmcnt dbuf pipeline + granule-XOR swizzle (r13/r14-verified, 0
// conflicts). MODE 0: QKV -> q (pre-scaled exp2 domain), k, vt[B,H,D,T].
// V-third blocks (j0>=2048) route the epilogue through an LDS transpose
// (stride-136 pad) so vt is written as 16B stores coalesced along t.
// MODE 1: out projection -> fp32 d_out.
template<int MODE>
__global__ __launch_bounds__(256) void gemm_bt(
    const ushort* __restrict__ A, const ushort* __restrict__ Bm,
    const float* __restrict__ bias, int K,
    ushort* __restrict__ q, ushort* __restrict__ kk, ushort* __restrict__ vt,
    float* __restrict__ outF)
{
  __shared__ ushort SM[17408];   // loop: A dbuf [0,8192) + B dbuf [8192,16384)
                                 // epilogue (V blocks): Lt[128][136]
  const int tid = threadIdx.x;
  const int lane = tid & 63;
  const int w = tid >> 6;
  const int wr = w >> 1, wc = w & 1;
  const int l15 = lane & 15, lhi = lane >> 4;
  const long i0 = (long)blockIdx.y * 128;
  const long j0 = (long)blockIdx.x * 128;

  const int gsw = (lhi ^ ((l15 >> 1) & 3)) * 8;

  auto STAGE = [&](int buf, int k0) {
    int c = tid;
    int row = c >> 2, gs = (c & 3) ^ ((row >> 1) & 3);
    ld16((const char*)A  + ((i0 + row) * K + k0 + gs * 8) * 2, (char*)SM + buf*8192 + c*16);
    ld16((const char*)Bm + ((j0 + row) * K + k0 + gs * 8) * 2, (char*)SM + 16384 + buf*8192 + c*16);
    c = tid + 256;
    row = c >> 2; gs = (c & 3) ^ ((row >> 1) & 3);
    ld16((const char*)A  + ((i0 + row) * K + k0 + gs * 8) * 2, (char*)SM + buf*8192 + c*16);
    ld16((const char*)Bm + ((j0 + row) * K + k0 + gs * 8) * 2, (char*)SM + 16384 + buf*8192 + c*16);
  };

  f32x4 acc[4][4] = {};
  const int nsteps = K >> 5;

  STAGE(0, 0);
  STAGE(1, 32);
  int cur = 0;

  for (int t = 0; t < nsteps; t++) {
    if (t + 1 < nsteps) { asm volatile("s_waitcnt vmcnt(4)" ::: "memory"); }
    else                { asm volatile("s_waitcnt vmcnt(0)" ::: "memory"); }
    __builtin_amdgcn_s_barrier();
    __builtin_amdgcn_sched_barrier(0);

    short8 af[4], bf[4];
#pragma unroll
    for (int m = 0; m < 4; m++)
      af[m] = *(const short8*)&SM[cur*4096 + (wr*64 + m*16 + l15)*32 + gsw];
#pragma unroll
    for (int n = 0; n < 4; n++)
      bf[n] = *(const short8*)&SM[8192 + cur*4096 + (wc*64 + n*16 + l15)*32 + gsw];
    __builtin_amdgcn_s_setprio(1);
#pragma unroll
    for (int m = 0; m < 4; m++)
#pragma unroll
      for (int n = 0; n < 4; n++)
        acc[m][n] = mfma16(af[m], bf[n], acc[m][n]);
    __builtin_amdgcn_s_setprio(0);

    __builtin_amdgcn_s_barrier();          // all waves done reading buf[cur]
    __builtin_amdgcn_sched_barrier(0);
    if (t + 2 < nsteps) STAGE(cur, (t + 2) * 32);
    cur ^= 1;
  }

  if (MODE == 0 && j0 >= 2048) {
    // ---- V block: LDS transpose epilogue ----
    // write: Lt[jl][tl] (stride 136), 4 packed bf16 per (m,n) via ds_write_b64
#pragma unroll
    for (int m = 0; m < 4; m++)
#pragma unroll
      for (int n = 0; n < 4; n++) {
        const int jl = wc*64 + n*16 + l15;
        const int tl = wr*64 + m*16 + lhi*4;
        const float bs = bias[j0 + jl];
        uint w0, w1;
        asm("v_cvt_pk_bf16_f32 %0, %1, %2" : "=v"(w0)
            : "v"(acc[m][n][0] + bs), "v"(acc[m][n][1] + bs));
        asm("v_cvt_pk_bf16_f32 %0, %1, %2" : "=v"(w1)
            : "v"(acc[m][n][2] + bs), "v"(acc[m][n][3] + bs));
        uint2 pr; pr.x = w0; pr.y = w1;
        *(uint2*)&SM[jl * 136 + tl] = pr;
      }
    __syncthreads();
    // read full t-rows, store coalesced along t
    const int b = (int)(i0 >> 11);
    const int tb = (int)(i0 & 2047);
#pragma unroll
    for (int k2 = 0; k2 < 8; k2++) {
      const int chunk = k2 * 256 + tid;      // 0..2047
      const int jl = chunk >> 4;
      const int t0 = (chunk & 15) * 8;
      uint4 pw = *(const uint4*)&SM[jl * 136 + t0];
      const int cc = (int)((j0 + jl) & 1023);
      const int h = cc >> 6, d = cc & 63;
      *(uint4*)&vt[((size_t)(b * H_ + h) * D_ + d) * T_ + tb + t0] = pw;
    }
  } else {
#pragma unroll
    for (int m = 0; m < 4; m++) {
#pragma unroll
      for (int n = 0; n < 4; n++) {
#pragma unroll
        for (int r = 0; r < 4; r++) {
          long i = i0 + wr*64 + m*16 + lhi*4 + r;       // token row
          int  j = (int)j0 + wc*64 + n*16 + l15;        // output feature
          float v = acc[m][n][r] + bias[j];
          if (MODE == 0) {
            int b = (int)(i >> 11), t = (int)(i & 2047);
            int cc = j & 1023;
            int h = cc >> 6, d = cc & 63;
            long bh = (long)b * H_ + h;
            if (j < 1024)      q [(bh*T_ + t)*D_ + d] = f2bf(v * SCALE_LOG2);
            else               kk[(bh*T_ + t)*D_ + d] = f2bf(v);
          } else {
            outF[i * C_ + j] = v;
          }
        }
      }
    }
  }
}

// ------------- causal flash attention, single-band blocks, KVBLK=128 -------------
// 1024 blocks x 256 threads (4 waves). head = bb&63 (same-head blocks share an
// XCD: bb%8 = head%8), rblk = 15 - (bb>>6) => longest blocks launch first and
// finishing blocks are backfilled by shorter ones (uniform drain). Wave w owns
// rows [128*rblk + 32w, +31]; nst = rblk+1 tiles of 128 kv.
// K[128][64] + Vt[64][128] double-buffered (counted vmcnt(8), XOR granule
// swizzle). QK = mfma32(K,Q); softmax in-register (shfl pair-reduce row max,
// unconditional rescale, lane-partial l); P via wave-private LDS relayout;
// PV = mfma32(Vt,P).
#define PSTR 20   // u32 per q-row: 16 pairs + 4 pad

static __device__ __forceinline__ void softmax_pack32(
    f32x16& sc, float& m, float& lp, f32x16 (&o)[2],
    int q0, int kvbase, int l31, int hi, uint* __restrict__ P)
{
  float sv[16];
  const bool needmask = (kvbase + 31 > q0);
#pragma unroll
  for (int r = 0; r < 16; r++) {
    float xv = sc[r];
    if (needmask) {
      int kv = kvbase + (r & 3) + 8 * (r >> 2) + 4 * hi;
      if (kv > q0 + l31) xv = -1e30f;
    }
    sv[r] = xv;
  }
  float p0 = fmaxf(fmaxf(sv[0], sv[1]),  fmaxf(sv[2], sv[3]));
  float p1 = fmaxf(fmaxf(sv[4], sv[5]),  fmaxf(sv[6], sv[7]));
  float p2 = fmaxf(fmaxf(sv[8], sv[9]),  fmaxf(sv[10], sv[11]));
  float p3 = fmaxf(fmaxf(sv[12], sv[13]), fmaxf(sv[14], sv[15]));
  float pm = fmaxf(fmaxf(p0, p1), fmaxf(p2, p3));
  float rowm = pair_max(pm);
  float nm = fmaxf(m, rowm);
  float alpha = __builtin_amdgcn_exp2f(m - nm);
  m = nm;
  lp *= alpha;
#pragma unroll
  for (int dt = 0; dt < 2; dt++)
#pragma unroll
    for (int r = 0; r < 16; r++) o[dt][r] *= alpha;
  float s = 0.f;
#pragma unroll
  for (int r = 0; r < 16; r++) {
    float p = __builtin_amdgcn_exp2f(sv[r] - m);
    sv[r] = p;
    s += p;
  }
  lp += s;
  uint W[8];
#pragma unroll
  for (int r = 0; r < 8; r++)
    asm("v_cvt_pk_bf16_f32 %0, %1, %2" : "=v"(W[r]) : "v"(sv[2*r]), "v"(sv[2*r+1]));
#pragma unroll
  for (int r2 = 0; r2 < 4; r2++) {
    uint2 pr; pr.x = W[2*r2]; pr.y = W[2*r2 + 1];
    *(uint2*)&P[l31 * PSTR + r2*4 + 2*hi] = pr;
  }
}

__global__ __launch_bounds__(256, 2) void attn_k(
    const ushort* __restrict__ Q, const ushort* __restrict__ K,
    const ushort* __restrict__ V, ushort* __restrict__ AO)
{
  __shared__ ushort Kt[2][128*64];
  __shared__ ushort Vt[2][64*128];
  __shared__ uint P2[4][32 * PSTR];
  const int tid = threadIdx.x;
  const int lane = tid & 63;
  const int w = tid >> 6;              // 0..3
  const int l31 = lane & 31, hi = lane >> 5;
  const int bb = blockIdx.x;
  const int head = bb & 63;            // bb%8 = head%8 -> same-head same XCD
  const int rblk = 15 - (bb >> 6);     // longest-first launch order
  const int nst = rblk + 1;            // kv tiles of 128
  const int q0 = 128 * rblk + 32 * w;

  const ushort* Qb = Q + (size_t)head * T_ * D_;
  const ushort* Kb = K + (size_t)head * T_ * D_;
  const ushort* Vb = V + (size_t)head * D_ * T_;   // [d][t]

  auto STAGE = [&](int buf, int kv0s) {
#pragma unroll
    for (int hb = 0; hb < 4; hb++) {
      int slot = tid + hb * 256;            // 0..1023
      int krow = slot >> 3, kg = slot & 7, kgs = kg ^ (krow & 7);
      ld16((const char*)Kb + ((size_t)(kv0s + krow) * D_ + kgs * 8) * 2,
           (char*)&Kt[buf][0] + slot * 16);
      int vrow = slot >> 4, vg = slot & 15, vgs = vg ^ (vrow & 15);
      ld16((const char*)Vb + ((size_t)vrow * T_ + kv0s + vgs * 8) * 2,
           (char*)&Vt[buf][0] + slot * 16);
    }
  };

  // Q as B-fragment: lane holds Q[q0+l31][d = s*16 + hi*8 + e] per slice s.
  short8 qf[4];
#pragma unroll
  for (int s = 0; s < 4; s++)
    qf[s] = *(const short8*)&Qb[(q0 + l31) * D_ + s*16 + hi*8];

  f32x16 o[2] = {};          // O'[d][q]: d = dt*32 + (r&3)+8(r>>2)+4hi
  float m = -1e30f, lp = 0.f;

  STAGE(0, 0);
  STAGE(1, 128);             // rows always valid; unused if nst==1
  int cur = 0;
  uint* P = &P2[w][0];

  for (int t = 0; t < nst; t++) {
    const int kv0 = t * 128;
    if (t + 1 < nst) { asm volatile("s_waitcnt vmcnt(8)" ::: "memory"); }
    else             { asm volatile("s_waitcnt vmcnt(0)" ::: "memory"); }
    __builtin_amdgcn_s_barrier();
    __builtin_amdgcn_sched_barrier(0);

#pragma unroll
    for (int c = 0; c < 4; c++) {
      const int kvc = kv0 + 32 * c;
      if (kvc <= q0 + 31) {
        // K A-fragment: lane holds K[c*32+l31][d = s*16 + hi*8 + e]
        short8 kf[4];
#pragma unroll
        for (int s = 0; s < 4; s++) {
          const int row = c*32 + l31;
          kf[s] = *(const short8*)&Kt[cur][row*64 + (((2*s + hi) ^ (row & 7)) << 3)];
        }
        // Vt A-fragment: Vt[dt*32+l31][kv = c*32 + sl*16 + hi*8 + e]
        short8 vf[2][2];
#pragma unroll
        for (int sl = 0; sl < 2; sl++)
#pragma unroll
          for (int dt = 0; dt < 2; dt++) {
            const int row = dt*32 + l31;
            const int u = c*4 + sl*2 + hi;
            vf[sl][dt] = *(const short8*)
                &Vt[cur][row*128 + ((u ^ (row & 15)) << 3)];
          }

        f32x16 sc = {};
        __builtin_amdgcn_s_setprio(1);
#pragma unroll
        for (int s = 0; s < 4; s++) sc = mfma32(kf[s], qf[s], sc);
        __builtin_amdgcn_s_setprio(0);
        softmax_pack32(sc, m, lp, o, q0, kvc, l31, hi, P);
        asm volatile("s_waitcnt lgkmcnt(0)" ::: "memory");
        __builtin_amdgcn_sched_barrier(0);
        short8 pf[2];
#pragma unroll
        for (int sl = 0; sl < 2; sl++) {
          uint4 pw = *(const uint4*)&P[l31 * PSTR + sl*8 + hi*4];
          __builtin_memcpy(&pf[sl], &pw, 16);
        }
        __builtin_amdgcn_s_setprio(1);
#pragma unroll
        for (int sl = 0; sl < 2; sl++)
#pragma unroll
          for (int dt = 0; dt < 2; dt++)
            o[dt] = mfma32(vf[sl][dt], pf[sl], o[dt]);
        __builtin_amdgcn_s_setprio(0);
        __builtin_amdgcn_sched_barrier(0);
      }
    }

    __builtin_amdgcn_s_barrier();
    __builtin_amdgcn_sched_barrier(0);
    if (t + 2 < nst) STAGE(cur, kv0 + 256);   // overwrite freed buffer
    cur ^= 1;
  }

  const int b = head >> 4, h = head & 15;
  const float invl = 1.0f / pair_sum(lp);
  const size_t rowb = (size_t)(b * T_ + q0 + l31) * C_ + h * 64;
#pragma unroll
  for (int dt = 0; dt < 2; dt++)
#pragma unroll
    for (int rg = 0; rg < 4; rg++) {
      const int d0 = dt*32 + 8*rg + 4*hi;
      ushort4 ov;
      ov.x = f2bf(o[dt][rg*4+0] * invl);
      ov.y = f2bf(o[dt][rg*4+1] * invl);
      ov.z = f2bf(o[dt][rg*4+2] * invl);
      ov.w = f2bf(o[dt][rg*4+3] * invl);
      *(ushort4*)&AO[rowb + d0] = ov;
    }
}

extern "C" void kernel_launch(void* const* d_in, const int* in_sizes, int n_in,
                              void* d_out, int out_size, void* d_ws, size_t ws_size,
                              hipStream_t stream) {
  const float* x     = (const float*)d_in[0];
  const float* w_qkv = (const float*)d_in[1];
  const float* b_qkv = (const float*)d_in[2];
  const float* w_out = (const float*)d_in[3];
  const float* b_out = (const float*)d_in[4];
  float* out = (float*)d_out;

  ushort* xb    = (ushort*)d_ws;                    // 8192*1024
  ushort* wqkvb = xb    + (size_t)M_ * C_;          // 3072*1024
  ushort* woutb = wqkvb + (size_t)3 * C_ * C_;      // 1024*1024
  ushort* q     = woutb + (size_t)C_ * C_;          // [B,H,T,D] (exp2-domain scaled)
  ushort* kk    = q     + (size_t)M_ * C_;          // [B,H,T,D]
  ushort* vt    = kk    + (size_t)M_ * C_;          // [B,H,D,T]
  ushort* ao    = xb;                               // reuse xb (free after QKV GEMM)

  cvt3<<<2048, 256, 0, stream>>>(x, w_qkv, w_out, xb, wqkvb, woutb,
                                 (M_ * C_) / 4, (3 * C_ * C_) / 4, (C_ * C_) / 4);

  gemm_bt<0><<<dim3(3 * C_ / 128, M_ / 128), 256, 0, stream>>>(
      xb, wqkvb, b_qkv, C_, q, kk, vt, nullptr);

  // 4 waves x 32 rows = 128 rows per block, one band -> 1024 blocks.
  attn_k<<<B_ * H_ * T_ / 128, 256, 0, stream>>>(q, kk, vt, ao);

  gemm_bt<1><<<dim3(C_ / 128, M_ / 128), 256, 0, stream>>>(
      ao, woutb, b_out, C_, nullptr, nullptr, nullptr, out);
}

// Round 16
// 175.771 us; speedup vs baseline: 1.8311x; 1.0502x over previous
//
#include <hip/hip_runtime.h>
#include <hip/hip_bf16.h>

// CausalSelfAttention: x[4,2048,1024] -> qkv proj -> 16-head causal attn -> out proj
// Pipeline: cvt3 -> gemm_bt<QKV> (counted vmcnt, XOR swizzle, LDS-transposed
// V epilogue) -> attn (paired mirror bands, KVBLK=64, defer-max) -> gemm_bt<OUT>

#define B_ 4
#define T_ 2048
#define C_ 1024
#define H_ 16
#define D_ 64
#define M_ (B_*T_)   // 8192 tokens

#define SCALE_LOG2 0.18033688f   // (1/sqrt(64)) * log2(e), folded into Q in GEMM

typedef __attribute__((ext_vector_type(8))) short short8;
typedef __attribute__((ext_vector_type(4))) float f32x4;
typedef __attribute__((ext_vector_type(16))) float f32x16;

static __device__ __forceinline__ ushort f2bf(float f) {
  __hip_bfloat16 b = __float2bfloat16(f);
  ushort u; __builtin_memcpy(&u, &b, 2); return u;
}

static __device__ __forceinline__ void ld16(const void* g, void* l) {
  __builtin_amdgcn_global_load_lds((const __attribute__((address_space(1))) void*)g,
                                   (__attribute__((address_space(3))) void*)l, 16, 0, 0);
}

static __device__ __forceinline__ f32x4 mfma16(short8 a, short8 b, f32x4 c) {
  return __builtin_amdgcn_mfma_f32_16x16x32_bf16(a, b, c, 0, 0, 0);
}
static __device__ __forceinline__ f32x16 mfma32(short8 a, short8 b, f32x16 c) {
  return __builtin_amdgcn_mfma_f32_32x32x16_bf16(a, b, c, 0, 0, 0);
}

static __device__ __forceinline__ float pair_max(float x) {
  return fmaxf(x, __shfl_xor(x, 32));
}
static __device__ __forceinline__ float pair_sum(float x) {
  return x + __shfl_xor(x, 32);
}

// ---------------- fp32 -> bf16 convert, all three tensors in one launch ----
__global__ void cvt3(const float* __restrict__ a, const float* __restrict__ b,
                     const float* __restrict__ c, ushort* __restrict__ oa,
                     ushort* __restrict__ ob, ushort* __restrict__ oc,
                     int na, int nb, int nc) {
  int tot = na + nb + nc;
  int i = blockIdx.x * blockDim.x + threadIdx.x;
  int st = gridDim.x * blockDim.x;
  for (; i < tot; i += st) {
    const float* s; ushort* d; int k = i;
    if (k < na)            { s = a; d = oa; }
    else if (k < na + nb)  { k -= na; s = b; d = ob; }
    else                   { k -= na + nb; s = c; d = oc; }
    float4 v = ((const float4*)s)[k];
    ushort4 o;
    o.x = f2bf(v.x); o.y = f2bf(v.y); o.z = f2bf(v.z); o.w = f2bf(v.w);
    ((ushort4*)d)[k] = o;
  }
}

// ---------------- C = A @ B^T + bias (both A,B K-major bf16) ----------------
// Counted-vmcnt dbuf pipeline + granule-XOR swizzle (0 conflicts). MODE 0:
// QKV -> q (pre-scaled exp2 domain), k, vt[B,H,D,T]; V-third blocks route the
// epilogue through an LDS transpose (stride-136) for coalesced-along-t stores.
// MODE 1: out projection -> fp32 d_out.
template<int MODE>
__global__ __launch_bounds__(256) void gemm_bt(
    const ushort* __restrict__ A, const ushort* __restrict__ Bm,
    const float* __restrict__ bias, int K,
    ushort* __restrict__ q, ushort* __restrict__ kk, ushort* __restrict__ vt,
    float* __restrict__ outF)
{
  __shared__ ushort SM[17408];
  const int tid = threadIdx.x;
  const int lane = tid & 63;
  const int w = tid >> 6;
  const int wr = w >> 1, wc = w & 1;
  const int l15 = lane & 15, lhi = lane >> 4;
  const long i0 = (long)blockIdx.y * 128;
  const long j0 = (long)blockIdx.x * 128;

  const int gsw = (lhi ^ ((l15 >> 1) & 3)) * 8;

  auto STAGE = [&](int buf, int k0) {
    int c = tid;
    int row = c >> 2, gs = (c & 3) ^ ((row >> 1) & 3);
    ld16((const char*)A  + ((i0 + row) * K + k0 + gs * 8) * 2, (char*)SM + buf*8192 + c*16);
    ld16((const char*)Bm + ((j0 + row) * K + k0 + gs * 8) * 2, (char*)SM + 16384 + buf*8192 + c*16);
    c = tid + 256;
    row = c >> 2; gs = (c & 3) ^ ((row >> 1) & 3);
    ld16((const char*)A  + ((i0 + row) * K + k0 + gs * 8) * 2, (char*)SM + buf*8192 + c*16);
    ld16((const char*)Bm + ((j0 + row) * K + k0 + gs * 8) * 2, (char*)SM + 16384 + buf*8192 + c*16);
  };

  f32x4 acc[4][4] = {};
  const int nsteps = K >> 5;

  STAGE(0, 0);
  STAGE(1, 32);
  int cur = 0;

  for (int t = 0; t < nsteps; t++) {
    if (t + 1 < nsteps) { asm volatile("s_waitcnt vmcnt(4)" ::: "memory"); }
    else                { asm volatile("s_waitcnt vmcnt(0)" ::: "memory"); }
    __builtin_amdgcn_s_barrier();
    __builtin_amdgcn_sched_barrier(0);

    short8 af[4], bf[4];
#pragma unroll
    for (int m = 0; m < 4; m++)
      af[m] = *(const short8*)&SM[cur*4096 + (wr*64 + m*16 + l15)*32 + gsw];
#pragma unroll
    for (int n = 0; n < 4; n++)
      bf[n] = *(const short8*)&SM[8192 + cur*4096 + (wc*64 + n*16 + l15)*32 + gsw];
    __builtin_amdgcn_s_setprio(1);
#pragma unroll
    for (int m = 0; m < 4; m++)
#pragma unroll
      for (int n = 0; n < 4; n++)
        acc[m][n] = mfma16(af[m], bf[n], acc[m][n]);
    __builtin_amdgcn_s_setprio(0);

    __builtin_amdgcn_s_barrier();
    __builtin_amdgcn_sched_barrier(0);
    if (t + 2 < nsteps) STAGE(cur, (t + 2) * 32);
    cur ^= 1;
  }

  if (MODE == 0 && j0 >= 2048) {
    // V block: LDS transpose epilogue (write [jl][tl] stride 136, read along t)
#pragma unroll
    for (int m = 0; m < 4; m++)
#pragma unroll
      for (int n = 0; n < 4; n++) {
        const int jl = wc*64 + n*16 + l15;
        const int tl = wr*64 + m*16 + lhi*4;
        const float bs = bias[j0 + jl];
        uint w0, w1;
        asm("v_cvt_pk_bf16_f32 %0, %1, %2" : "=v"(w0)
            : "v"(acc[m][n][0] + bs), "v"(acc[m][n][1] + bs));
        asm("v_cvt_pk_bf16_f32 %0, %1, %2" : "=v"(w1)
            : "v"(acc[m][n][2] + bs), "v"(acc[m][n][3] + bs));
        uint2 pr; pr.x = w0; pr.y = w1;
        *(uint2*)&SM[jl * 136 + tl] = pr;
      }
    __syncthreads();
    const int b = (int)(i0 >> 11);
    const int tb = (int)(i0 & 2047);
#pragma unroll
    for (int k2 = 0; k2 < 8; k2++) {
      const int chunk = k2 * 256 + tid;
      const int jl = chunk >> 4;
      const int t0 = (chunk & 15) * 8;
      uint4 pw = *(const uint4*)&SM[jl * 136 + t0];
      const int cc = (int)((j0 + jl) & 1023);
      const int h = cc >> 6, d = cc & 63;
      *(uint4*)&vt[((size_t)(b * H_ + h) * D_ + d) * T_ + tb + t0] = pw;
    }
  } else {
#pragma unroll
    for (int m = 0; m < 4; m++) {
#pragma unroll
      for (int n = 0; n < 4; n++) {
#pragma unroll
        for (int r = 0; r < 4; r++) {
          long i = i0 + wr*64 + m*16 + lhi*4 + r;
          int  j = (int)j0 + wc*64 + n*16 + l15;
          float v = acc[m][n][r] + bias[j];
          if (MODE == 0) {
            int b = (int)(i >> 11), t = (int)(i & 2047);
            int cc = j & 1023;
            int h = cc >> 6, d = cc & 63;
            long bh = (long)b * H_ + h;
            if (j < 1024)      q [(bh*T_ + t)*D_ + d] = f2bf(v * SCALE_LOG2);
            else               kk[(bh*T_ + t)*D_ + d] = f2bf(v);
          } else {
            outF[i * C_ + j] = v;
          }
        }
      }
    }
  }
}

// ------- causal flash attention, paired mirror bands, KVBLK=64, defer-max -------
// 512 blocks x 256 threads (4 waves). head = bb&63 (8 heads/XCD), i = bb>>6,
// J = i<4 ? i : 11-i (co-resident bb, bb+256 sum to constant work). Wave w:
// band a rows [128J+32w,+31], band b rows mirror. K[64][64] + Vt[64][64]
// double-buffered (counted vmcnt(4), XOR granule swizzle). Per 32-kv chunk:
// QK=mfma32(K,Q); defer-max softmax (rescale only when __any(pmax>m+8); lane-
// partial l); P via wave-private LDS (PSTR=20, 16B-slot XOR bank fix on both
// sides); PV=mfma32(Vt,P). LDS 42KB -> 3 blocks/CU.
#define PSTR 20   // u32 per q-row: 16 pairs + 4 pad

static __device__ __forceinline__ void softmax_pack32(
    f32x16& sc, float& m, float& lp, f32x16 (&o)[2],
    int q0, int kvbase, int l31, int hi, uint* __restrict__ P)
{
  const int sx = ((l31 >> 3) & 3) << 2;     // bank-fix XOR (row-determined)
  float sv[16];
  const bool needmask = (kvbase + 31 > q0);
#pragma unroll
  for (int r = 0; r < 16; r++) {
    float xv = sc[r];
    if (needmask) {
      int kv = kvbase + (r & 3) + 8 * (r >> 2) + 4 * hi;
      if (kv > q0 + l31) xv = -1e30f;
    }
    sv[r] = xv;
  }
  // lane max via max3-friendly triples
  float a0 = fmaxf(fmaxf(sv[0], sv[1]), sv[2]);
  float a1 = fmaxf(fmaxf(sv[3], sv[4]), sv[5]);
  float a2 = fmaxf(fmaxf(sv[6], sv[7]), sv[8]);
  float a3 = fmaxf(fmaxf(sv[9], sv[10]), sv[11]);
  float a4 = fmaxf(fmaxf(sv[12], sv[13]), sv[14]);
  float pmax = fmaxf(fmaxf(fmaxf(a0, a1), a2), fmaxf(fmaxf(a3, a4), sv[15]));
  // defer-max: rare rescale only on significant growth
  if (__any(pmax > m + 8.0f)) {
    float rowm = pair_max(pmax);
    float nm = fmaxf(m, rowm);
    float alpha = __builtin_amdgcn_exp2f(m - nm);
    m = nm;
    lp *= alpha;
#pragma unroll
    for (int dt = 0; dt < 2; dt++)
#pragma unroll
      for (int r = 0; r < 16; r++) o[dt][r] *= alpha;
  }
  float s = 0.f;
#pragma unroll
  for (int r = 0; r < 16; r++) {
    float p = __builtin_amdgcn_exp2f(sv[r] - m);
    sv[r] = p;
    s += p;
  }
  lp += s;
  uint W[8];
#pragma unroll
  for (int r = 0; r < 8; r++)
    asm("v_cvt_pk_bf16_f32 %0, %1, %2" : "=v"(W[r]) : "v"(sv[2*r]), "v"(sv[2*r+1]));
#pragma unroll
  for (int r2 = 0; r2 < 4; r2++) {
    uint2 pr; pr.x = W[2*r2]; pr.y = W[2*r2 + 1];
    *(uint2*)&P[l31 * PSTR + ((r2*4) ^ sx) + 2*hi] = pr;
  }
}

__global__ __launch_bounds__(256, 2) void attn_k(
    const ushort* __restrict__ Q, const ushort* __restrict__ K,
    const ushort* __restrict__ V, ushort* __restrict__ AO)
{
  __shared__ ushort Kt[2][64*64];
  __shared__ ushort Vt[2][64*64];
  __shared__ uint P2[4][32 * PSTR];
  const int tid = threadIdx.x;
  const int lane = tid & 63;
  const int w = tid >> 6;              // 0..3
  const int l31 = lane & 31, hi = lane >> 5;
  const int sx = ((l31 >> 3) & 3) << 2;
  const int bb = blockIdx.x;
  const int head = bb & 63;            // bb%8 = head%8 -> same-head same XCD
  const int i = bb >> 6;               // 0..7
  const int J = (i < 4) ? i : 11 - i;  // complementary pairing bb, bb+256
  const int nst = 32 - 2 * J;          // 64-kv tiles (>= 18)
  const int q0a = 128 * J + 32 * w;            // low band
  const int q0b = 2016 - 128 * J - 32 * w;     // high (mirror) band

  const ushort* Qb = Q + (size_t)head * T_ * D_;
  const ushort* Kb = K + (size_t)head * T_ * D_;
  const ushort* Vb = V + (size_t)head * D_ * T_;   // [d][t]

  auto STAGE = [&](int buf, int kv0s) {
#pragma unroll
    for (int hb = 0; hb < 2; hb++) {
      int slot = tid + hb * 256;            // 0..511
      int row = slot >> 3, g = slot & 7, gs = g ^ (row & 7);
      ld16((const char*)Kb + ((size_t)(kv0s + row) * D_ + gs * 8) * 2,
           (char*)&Kt[buf][0] + slot * 16);
      ld16((const char*)Vb + ((size_t)row * T_ + kv0s + gs * 8) * 2,
           (char*)&Vt[buf][0] + slot * 16);
    }
  };

  // Q as B-fragment: lane holds Q[q0+l31][d = s*16 + hi*8 + e] per slice s.
  short8 qfa[4], qfb[4];
#pragma unroll
  for (int s = 0; s < 4; s++) {
    qfa[s] = *(const short8*)&Qb[(q0a + l31) * D_ + s*16 + hi*8];
    qfb[s] = *(const short8*)&Qb[(q0b + l31) * D_ + s*16 + hi*8];
  }

  f32x16 oa[2] = {}, ob[2] = {};       // O'[d][q]: d = dt*32 + (r&3)+8(r>>2)+4hi
  float ma = -1e30f, la = 0.f, mb = -1e30f, lb = 0.f;

  STAGE(0, 0);
  STAGE(1, 64);
  int cur = 0;
  uint* P = &P2[w][0];

  for (int t = 0; t < nst; t++) {
    const int kv0 = t * 64;
    if (t + 1 < nst) { asm volatile("s_waitcnt vmcnt(4)" ::: "memory"); }
    else             { asm volatile("s_waitcnt vmcnt(0)" ::: "memory"); }
    __builtin_amdgcn_s_barrier();
    __builtin_amdgcn_sched_barrier(0);

#pragma unroll
    for (int c = 0; c < 2; c++) {
      const int kvc = kv0 + 32 * c;
      const bool act_b = (kvc <= q0b + 31);
      const bool act_a = (kvc <= q0a + 31);   // act_a implies act_b
      if (act_b) {
        // K A-fragment: lane holds K[c*32+l31][d = s*16 + hi*8 + e]
        short8 kf[4];
#pragma unroll
        for (int s = 0; s < 4; s++) {
          const int row = c*32 + l31;
          kf[s] = *(const short8*)&Kt[cur][row*64 + (((2*s + hi) ^ (row & 7)) << 3)];
        }
        // Vt A-fragment: Vt[dt*32+l31][kv = c*32 + sl*16 + hi*8 + e]
        short8 vf[2][2];
#pragma unroll
        for (int sl = 0; sl < 2; sl++)
#pragma unroll
          for (int dt = 0; dt < 2; dt++) {
            const int row = dt*32 + l31;
            const int u = c*4 + sl*2 + hi;
            vf[sl][dt] = *(const short8*)&Vt[cur][row*64 + ((u ^ (row & 7)) << 3)];
          }

        // ---- band b ----
        {
          f32x16 scb = {};
          __builtin_amdgcn_s_setprio(1);
#pragma unroll
          for (int s = 0; s < 4; s++) scb = mfma32(kf[s], qfb[s], scb);
          __builtin_amdgcn_s_setprio(0);
          softmax_pack32(scb, mb, lb, ob, q0b, kvc, l31, hi, P);
          asm volatile("s_waitcnt lgkmcnt(0)" ::: "memory");
          __builtin_amdgcn_sched_barrier(0);
          short8 pf[2];
#pragma unroll
          for (int sl = 0; sl < 2; sl++) {
            uint4 pw = *(const uint4*)&P[l31 * PSTR + ((sl*8 + hi*4) ^ sx)];
            __builtin_memcpy(&pf[sl], &pw, 16);
          }
          __builtin_amdgcn_s_setprio(1);
#pragma unroll
          for (int sl = 0; sl < 2; sl++)
#pragma unroll
            for (int dt = 0; dt < 2; dt++)
              ob[dt] = mfma32(vf[sl][dt], pf[sl], ob[dt]);
          __builtin_amdgcn_s_setprio(0);
          __builtin_amdgcn_sched_barrier(0);
        }
        // ---- band a (reuses kf, vf, P buffer) ----
        if (act_a) {
          f32x16 sca = {};
          __builtin_amdgcn_s_setprio(1);
#pragma unroll
          for (int s = 0; s < 4; s++) sca = mfma32(kf[s], qfa[s], sca);
          __builtin_amdgcn_s_setprio(0);
          softmax_pack32(sca, ma, la, oa, q0a, kvc, l31, hi, P);
          asm volatile("s_waitcnt lgkmcnt(0)" ::: "memory");
          __builtin_amdgcn_sched_barrier(0);
          short8 pf[2];
#pragma unroll
          for (int sl = 0; sl < 2; sl++) {
            uint4 pw = *(const uint4*)&P[l31 * PSTR + ((sl*8 + hi*4) ^ sx)];
            __builtin_memcpy(&pf[sl], &pw, 16);
          }
          __builtin_amdgcn_s_setprio(1);
#pragma unroll
          for (int sl = 0; sl < 2; sl++)
#pragma unroll
            for (int dt = 0; dt < 2; dt++)
              oa[dt] = mfma32(vf[sl][dt], pf[sl], oa[dt]);
          __builtin_amdgcn_s_setprio(0);
          __builtin_amdgcn_sched_barrier(0);
        }
      }
    }

    __builtin_amdgcn_s_barrier();
    __builtin_amdgcn_sched_barrier(0);
    if (t + 2 < nst) STAGE(cur, kv0 + 128);   // overwrite freed buffer
    cur ^= 1;
  }

  const int b = head >> 4, h = head & 15;
  {
    const float invl = 1.0f / pair_sum(lb);
    const size_t rowb = (size_t)(b * T_ + q0b + l31) * C_ + h * 64;
#pragma unroll
    for (int dt = 0; dt < 2; dt++)
#pragma unroll
      for (int rg = 0; rg < 4; rg++) {
        const int d0 = dt*32 + 8*rg + 4*hi;
        ushort4 ov;
        ov.x = f2bf(ob[dt][rg*4+0] * invl);
        ov.y = f2bf(ob[dt][rg*4+1] * invl);
        ov.z = f2bf(ob[dt][rg*4+2] * invl);
        ov.w = f2bf(ob[dt][rg*4+3] * invl);
        *(ushort4*)&AO[rowb + d0] = ov;
      }
  }
  {
    const float invl = 1.0f / pair_sum(la);
    const size_t rowb = (size_t)(b * T_ + q0a + l31) * C_ + h * 64;
#pragma unroll
    for (int dt = 0; dt < 2; dt++)
#pragma unroll
      for (int rg = 0; rg < 4; rg++) {
        const int d0 = dt*32 + 8*rg + 4*hi;
        ushort4 ov;
        ov.x = f2bf(oa[dt][rg*4+0] * invl);
        ov.y = f2bf(oa[dt][rg*4+1] * invl);
        ov.z = f2bf(oa[dt][rg*4+2] * invl);
        ov.w = f2bf(oa[dt][rg*4+3] * invl);
        *(ushort4*)&AO[rowb + d0] = ov;
      }
  }
}

extern "C" void kernel_launch(void* const* d_in, const int* in_sizes, int n_in,
                              void* d_out, int out_size, void* d_ws, size_t ws_size,
                              hipStream_t stream) {
  const float* x     = (const float*)d_in[0];
  const float* w_qkv = (const float*)d_in[1];
  const float* b_qkv = (const float*)d_in[2];
  const float* w_out = (const float*)d_in[3];
  const float* b_out = (const float*)d_in[4];
  float* out = (float*)d_out;

  ushort* xb    = (ushort*)d_ws;                    // 8192*1024
  ushort* wqkvb = xb    + (size_t)M_ * C_;          // 3072*1024
  ushort* woutb = wqkvb + (size_t)3 * C_ * C_;      // 1024*1024
  ushort* q     = woutb + (size_t)C_ * C_;          // [B,H,T,D] (exp2-domain scaled)
  ushort* kk    = q     + (size_t)M_ * C_;          // [B,H,T,D]
  ushort* vt    = kk    + (size_t)M_ * C_;          // [B,H,D,T]
  ushort* ao    = xb;                               // reuse xb (free after QKV GEMM)

  cvt3<<<2048, 256, 0, stream>>>(x, w_qkv, w_out, xb, wqkvb, woutb,
                                 (M_ * C_) / 4, (3 * C_ * C_) / 4, (C_ * C_) / 4);

  gemm_bt<0><<<dim3(3 * C_ / 128, M_ / 128), 256, 0, stream>>>(
      xb, wqkvb, b_qkv, C_, q, kk, vt, nullptr);

  // 4 waves x (32 low + 32 high) rows = 256 rows per block -> 512 blocks.
  attn_k<<<B_ * H_ * T_ / 256, 256, 0, stream>>>(q, kk, vt, ao);

  gemm_bt<1><<<dim3(C_ / 128, M_ / 128), 256, 0, stream>>>(
      ao, woutb, b_out, C_, nullptr, nullptr, nullptr, out);
}

// Round 17
// 171.008 us; speedup vs baseline: 1.8821x; 1.0278x over previous
//
#include <hip/hip_runtime.h>
#include <hip/hip_bf16.h>

// CausalSelfAttention: x[4,2048,1024] -> qkv proj -> 16-head causal attn -> out proj
// Pipeline: cvt3 -> gemm_bt<QKV> (counted vmcnt, XOR swizzle, LDS-transposed
// V epilogue) -> attn (paired bands, KVBLK=128, defer-max) -> gemm_bt<OUT>

#define B_ 4
#define T_ 2048
#define C_ 1024
#define H_ 16
#define D_ 64
#define M_ (B_*T_)   // 8192 tokens

#define SCALE_LOG2 0.18033688f   // (1/sqrt(64)) * log2(e), folded into Q in GEMM

typedef __attribute__((ext_vector_type(8))) short short8;
typedef __attribute__((ext_vector_type(4))) float f32x4;
typedef __attribute__((ext_vector_type(16))) float f32x16;

static __device__ __forceinline__ ushort f2bf(float f) {
  __hip_bfloat16 b = __float2bfloat16(f);
  ushort u; __builtin_memcpy(&u, &b, 2); return u;
}

static __device__ __forceinline__ void ld16(const void* g, void* l) {
  __builtin_amdgcn_global_load_lds((const __attribute__((address_space(1))) void*)g,
                                   (__attribute__((address_space(3))) void*)l, 16, 0, 0);
}

static __device__ __forceinline__ f32x4 mfma16(short8 a, short8 b, f32x4 c) {
  return __builtin_amdgcn_mfma_f32_16x16x32_bf16(a, b, c, 0, 0, 0);
}
static __device__ __forceinline__ f32x16 mfma32(short8 a, short8 b, f32x16 c) {
  return __builtin_amdgcn_mfma_f32_32x32x16_bf16(a, b, c, 0, 0, 0);
}

static __device__ __forceinline__ float pair_max(float x) {
  return fmaxf(x, __shfl_xor(x, 32));
}
static __device__ __forceinline__ float pair_sum(float x) {
  return x + __shfl_xor(x, 32);
}

// ---------------- fp32 -> bf16 convert, all three tensors in one launch ----
__global__ void cvt3(const float* __restrict__ a, const float* __restrict__ b,
                     const float* __restrict__ c, ushort* __restrict__ oa,
                     ushort* __restrict__ ob, ushort* __restrict__ oc,
                     int na, int nb, int nc) {
  int tot = na + nb + nc;
  int i = blockIdx.x * blockDim.x + threadIdx.x;
  int st = gridDim.x * blockDim.x;
  for (; i < tot; i += st) {
    const float* s; ushort* d; int k = i;
    if (k < na)            { s = a; d = oa; }
    else if (k < na + nb)  { k -= na; s = b; d = ob; }
    else                   { k -= na + nb; s = c; d = oc; }
    float4 v = ((const float4*)s)[k];
    ushort4 o;
    o.x = f2bf(v.x); o.y = f2bf(v.y); o.z = f2bf(v.z); o.w = f2bf(v.w);
    ((ushort4*)d)[k] = o;
  }
}

// ---------------- C = A @ B^T + bias (both A,B K-major bf16) ----------------
// Counted-vmcnt dbuf pipeline + granule-XOR swizzle (0 conflicts). MODE 0:
// QKV -> q (pre-scaled exp2 domain), k, vt[B,H,D,T]; V-third blocks route the
// epilogue through an LDS transpose (stride-136) for coalesced-along-t stores.
// MODE 1: out projection -> fp32 d_out.
template<int MODE>
__global__ __launch_bounds__(256) void gemm_bt(
    const ushort* __restrict__ A, const ushort* __restrict__ Bm,
    const float* __restrict__ bias, int K,
    ushort* __restrict__ q, ushort* __restrict__ kk, ushort* __restrict__ vt,
    float* __restrict__ outF)
{
  __shared__ ushort SM[17408];
  const int tid = threadIdx.x;
  const int lane = tid & 63;
  const int w = tid >> 6;
  const int wr = w >> 1, wc = w & 1;
  const int l15 = lane & 15, lhi = lane >> 4;
  const long i0 = (long)blockIdx.y * 128;
  const long j0 = (long)blockIdx.x * 128;

  const int gsw = (lhi ^ ((l15 >> 1) & 3)) * 8;

  auto STAGE = [&](int buf, int k0) {
    int c = tid;
    int row = c >> 2, gs = (c & 3) ^ ((row >> 1) & 3);
    ld16((const char*)A  + ((i0 + row) * K + k0 + gs * 8) * 2, (char*)SM + buf*8192 + c*16);
    ld16((const char*)Bm + ((j0 + row) * K + k0 + gs * 8) * 2, (char*)SM + 16384 + buf*8192 + c*16);
    c = tid + 256;
    row = c >> 2; gs = (c & 3) ^ ((row >> 1) & 3);
    ld16((const char*)A  + ((i0 + row) * K + k0 + gs * 8) * 2, (char*)SM + buf*8192 + c*16);
    ld16((const char*)Bm + ((j0 + row) * K + k0 + gs * 8) * 2, (char*)SM + 16384 + buf*8192 + c*16);
  };

  f32x4 acc[4][4] = {};
  const int nsteps = K >> 5;

  STAGE(0, 0);
  STAGE(1, 32);
  int cur = 0;

  for (int t = 0; t < nsteps; t++) {
    if (t + 1 < nsteps) { asm volatile("s_waitcnt vmcnt(4)" ::: "memory"); }
    else                { asm volatile("s_waitcnt vmcnt(0)" ::: "memory"); }
    __builtin_amdgcn_s_barrier();
    __builtin_amdgcn_sched_barrier(0);

    short8 af[4], bf[4];
#pragma unroll
    for (int m = 0; m < 4; m++)
      af[m] = *(const short8*)&SM[cur*4096 + (wr*64 + m*16 + l15)*32 + gsw];
#pragma unroll
    for (int n = 0; n < 4; n++)
      bf[n] = *(const short8*)&SM[8192 + cur*4096 + (wc*64 + n*16 + l15)*32 + gsw];
    __builtin_amdgcn_s_setprio(1);
#pragma unroll
    for (int m = 0; m < 4; m++)
#pragma unroll
      for (int n = 0; n < 4; n++)
        acc[m][n] = mfma16(af[m], bf[n], acc[m][n]);
    __builtin_amdgcn_s_setprio(0);

    __builtin_amdgcn_s_barrier();
    __builtin_amdgcn_sched_barrier(0);
    if (t + 2 < nsteps) STAGE(cur, (t + 2) * 32);
    cur ^= 1;
  }

  if (MODE == 0 && j0 >= 2048) {
    // V block: LDS transpose epilogue (write [jl][tl] stride 136, read along t)
#pragma unroll
    for (int m = 0; m < 4; m++)
#pragma unroll
      for (int n = 0; n < 4; n++) {
        const int jl = wc*64 + n*16 + l15;
        const int tl = wr*64 + m*16 + lhi*4;
        const float bs = bias[j0 + jl];
        uint w0, w1;
        asm("v_cvt_pk_bf16_f32 %0, %1, %2" : "=v"(w0)
            : "v"(acc[m][n][0] + bs), "v"(acc[m][n][1] + bs));
        asm("v_cvt_pk_bf16_f32 %0, %1, %2" : "=v"(w1)
            : "v"(acc[m][n][2] + bs), "v"(acc[m][n][3] + bs));
        uint2 pr; pr.x = w0; pr.y = w1;
        *(uint2*)&SM[jl * 136 + tl] = pr;
      }
    __syncthreads();
    const int b = (int)(i0 >> 11);
    const int tb = (int)(i0 & 2047);
#pragma unroll
    for (int k2 = 0; k2 < 8; k2++) {
      const int chunk = k2 * 256 + tid;
      const int jl = chunk >> 4;
      const int t0 = (chunk & 15) * 8;
      uint4 pw = *(const uint4*)&SM[jl * 136 + t0];
      const int cc = (int)((j0 + jl) & 1023);
      const int h = cc >> 6, d = cc & 63;
      *(uint4*)&vt[((size_t)(b * H_ + h) * D_ + d) * T_ + tb + t0] = pw;
    }
  } else {
#pragma unroll
    for (int m = 0; m < 4; m++) {
#pragma unroll
      for (int n = 0; n < 4; n++) {
#pragma unroll
        for (int r = 0; r < 4; r++) {
          long i = i0 + wr*64 + m*16 + lhi*4 + r;
          int  j = (int)j0 + wc*64 + n*16 + l15;
          float v = acc[m][n][r] + bias[j];
          if (MODE == 0) {
            int b = (int)(i >> 11), t = (int)(i & 2047);
            int cc = j & 1023;
            int h = cc >> 6, d = cc & 63;
            long bh = (long)b * H_ + h;
            if (j < 1024)      q [(bh*T_ + t)*D_ + d] = f2bf(v * SCALE_LOG2);
            else               kk[(bh*T_ + t)*D_ + d] = f2bf(v);
          } else {
            outF[i * C_ + j] = v;
          }
        }
      }
    }
  }
}

// ------- causal flash attention, paired bands, KVBLK=128, defer-max -------
// 512 blocks x 256 threads (4 waves). head = bb&63 (8 heads/XCD), i = bb>>6,
// J = i<4 ? i : 11-i (co-resident bb, bb+256 sum to constant work). Wave w:
// band a rows [128J+32w,+31], band b rows mirror. K[128][64] + Vt[64][128]
// double-buffered (counted vmcnt(8), XOR granule swizzle: K g^(row&7),
// V g^(row&15)). Per 32-kv chunk: QK=mfma32(K,Q); defer-max softmax (rescale
// only when __any(pmax>m+8); lane-partial l); bands sequential sharing one
// wave-private P buffer (PSTR=20); PV=mfma32(Vt,P). LDS 74KB -> 2 blocks/CU.
#define PSTR 20   // u32 per q-row: 16 pairs + 4 pad

static __device__ __forceinline__ void softmax_pack32(
    f32x16& sc, float& m, float& lp, f32x16 (&o)[2],
    int q0, int kvbase, int l31, int hi, uint* __restrict__ P)
{
  float sv[16];
  const bool needmask = (kvbase + 31 > q0);
#pragma unroll
  for (int r = 0; r < 16; r++) {
    float xv = sc[r];
    if (needmask) {
      int kv = kvbase + (r & 3) + 8 * (r >> 2) + 4 * hi;
      if (kv > q0 + l31) xv = -1e30f;
    }
    sv[r] = xv;
  }
  // lane max via max3-friendly triples
  float a0 = fmaxf(fmaxf(sv[0], sv[1]), sv[2]);
  float a1 = fmaxf(fmaxf(sv[3], sv[4]), sv[5]);
  float a2 = fmaxf(fmaxf(sv[6], sv[7]), sv[8]);
  float a3 = fmaxf(fmaxf(sv[9], sv[10]), sv[11]);
  float a4 = fmaxf(fmaxf(sv[12], sv[13]), sv[14]);
  float pmax = fmaxf(fmaxf(fmaxf(a0, a1), a2), fmaxf(fmaxf(a3, a4), sv[15]));
  // defer-max: rare rescale only on significant growth
  if (__any(pmax > m + 8.0f)) {
    float rowm = pair_max(pmax);
    float nm = fmaxf(m, rowm);
    float alpha = __builtin_amdgcn_exp2f(m - nm);
    m = nm;
    lp *= alpha;
#pragma unroll
    for (int dt = 0; dt < 2; dt++)
#pragma unroll
      for (int r = 0; r < 16; r++) o[dt][r] *= alpha;
  }
  float s = 0.f;
#pragma unroll
  for (int r = 0; r < 16; r++) {
    float p = __builtin_amdgcn_exp2f(sv[r] - m);
    sv[r] = p;
    s += p;
  }
  lp += s;
  uint W[8];
#pragma unroll
  for (int r = 0; r < 8; r++)
    asm("v_cvt_pk_bf16_f32 %0, %1, %2" : "=v"(W[r]) : "v"(sv[2*r]), "v"(sv[2*r+1]));
#pragma unroll
  for (int r2 = 0; r2 < 4; r2++) {
    uint2 pr; pr.x = W[2*r2]; pr.y = W[2*r2 + 1];
    *(uint2*)&P[l31 * PSTR + r2*4 + 2*hi] = pr;
  }
}

__global__ __launch_bounds__(256, 2) void attn_k(
    const ushort* __restrict__ Q, const ushort* __restrict__ K,
    const ushort* __restrict__ V, ushort* __restrict__ AO)
{
  __shared__ ushort Kt[2][128*64];
  __shared__ ushort Vt[2][64*128];
  __shared__ uint P2[4][32 * PSTR];
  const int tid = threadIdx.x;
  const int lane = tid & 63;
  const int w = tid >> 6;              // 0..3
  const int l31 = lane & 31, hi = lane >> 5;
  const int bb = blockIdx.x;
  const int head = bb & 63;            // bb%8 = head%8 -> same-head same XCD
  const int i = bb >> 6;               // 0..7
  const int J = (i < 4) ? i : 11 - i;  // complementary pairing bb, bb+256
  const int nst = 16 - J;              // 128-kv tiles (>= 9)
  const int q0a = 128 * J + 32 * w;            // low band
  const int q0b = 2016 - 128 * J - 32 * w;     // high (mirror) band

  const ushort* Qb = Q + (size_t)head * T_ * D_;
  const ushort* Kb = K + (size_t)head * T_ * D_;
  const ushort* Vb = V + (size_t)head * D_ * T_;   // [d][t]

  auto STAGE = [&](int buf, int kv0s) {
#pragma unroll
    for (int hb = 0; hb < 4; hb++) {
      int slot = tid + hb * 256;            // 0..1023
      int krow = slot >> 3, kg = slot & 7, kgs = kg ^ (krow & 7);
      ld16((const char*)Kb + ((size_t)(kv0s + krow) * D_ + kgs * 8) * 2,
           (char*)&Kt[buf][0] + slot * 16);
      int vrow = slot >> 4, vg = slot & 15, vgs = vg ^ (vrow & 15);
      ld16((const char*)Vb + ((size_t)vrow * T_ + kv0s + vgs * 8) * 2,
           (char*)&Vt[buf][0] + slot * 16);
    }
  };

  // Q as B-fragment: lane holds Q[q0+l31][d = s*16 + hi*8 + e] per slice s.
  short8 qfa[4], qfb[4];
#pragma unroll
  for (int s = 0; s < 4; s++) {
    qfa[s] = *(const short8*)&Qb[(q0a + l31) * D_ + s*16 + hi*8];
    qfb[s] = *(const short8*)&Qb[(q0b + l31) * D_ + s*16 + hi*8];
  }

  f32x16 oa[2] = {}, ob[2] = {};       // O'[d][q]: d = dt*32 + (r&3)+8(r>>2)+4hi
  float ma = -1e30f, la = 0.f, mb = -1e30f, lb = 0.f;

  STAGE(0, 0);
  STAGE(1, 128);
  int cur = 0;
  uint* P = &P2[w][0];

  for (int t = 0; t < nst; t++) {
    const int kv0 = t * 128;
    if (t + 1 < nst) { asm volatile("s_waitcnt vmcnt(8)" ::: "memory"); }
    else             { asm volatile("s_waitcnt vmcnt(0)" ::: "memory"); }
    __builtin_amdgcn_s_barrier();
    __builtin_amdgcn_sched_barrier(0);

#pragma unroll
    for (int c = 0; c < 4; c++) {
      const int kvc = kv0 + 32 * c;
      const bool act_b = (kvc <= q0b + 31);
      const bool act_a = (kvc <= q0a + 31);   // act_a implies act_b
      if (act_b) {
        // K A-fragment: lane holds K[c*32+l31][d = s*16 + hi*8 + e]
        short8 kf[4];
#pragma unroll
        for (int s = 0; s < 4; s++) {
          const int row = c*32 + l31;
          kf[s] = *(const short8*)&Kt[cur][row*64 + (((2*s + hi) ^ (row & 7)) << 3)];
        }
        // Vt A-fragment: Vt[dt*32+l31][kv = c*32 + sl*16 + hi*8 + e]
        short8 vf[2][2];
#pragma unroll
        for (int sl = 0; sl < 2; sl++)
#pragma unroll
          for (int dt = 0; dt < 2; dt++) {
            const int row = dt*32 + l31;
            const int u = c*4 + sl*2 + hi;
            vf[sl][dt] = *(const short8*)
                &Vt[cur][row*128 + ((u ^ (row & 15)) << 3)];
          }

        // ---- band b ----
        {
          f32x16 scb = {};
          __builtin_amdgcn_s_setprio(1);
#pragma unroll
          for (int s = 0; s < 4; s++) scb = mfma32(kf[s], qfb[s], scb);
          __builtin_amdgcn_s_setprio(0);
          softmax_pack32(scb, mb, lb, ob, q0b, kvc, l31, hi, P);
          asm volatile("s_waitcnt lgkmcnt(0)" ::: "memory");
          __builtin_amdgcn_sched_barrier(0);
          short8 pf[2];
#pragma unroll
          for (int sl = 0; sl < 2; sl++) {
            uint4 pw = *(const uint4*)&P[l31 * PSTR + sl*8 + hi*4];
            __builtin_memcpy(&pf[sl], &pw, 16);
          }
          __builtin_amdgcn_s_setprio(1);
#pragma unroll
          for (int sl = 0; sl < 2; sl++)
#pragma unroll
            for (int dt = 0; dt < 2; dt++)
              ob[dt] = mfma32(vf[sl][dt], pf[sl], ob[dt]);
          __builtin_amdgcn_s_setprio(0);
          __builtin_amdgcn_sched_barrier(0);
        }
        // ---- band a (reuses kf, vf, P buffer) ----
        if (act_a) {
          f32x16 sca = {};
          __builtin_amdgcn_s_setprio(1);
#pragma unroll
          for (int s = 0; s < 4; s++) sca = mfma32(kf[s], qfa[s], sca);
          __builtin_amdgcn_s_setprio(0);
          softmax_pack32(sca, ma, la, oa, q0a, kvc, l31, hi, P);
          asm volatile("s_waitcnt lgkmcnt(0)" ::: "memory");
          __builtin_amdgcn_sched_barrier(0);
          short8 pf[2];
#pragma unroll
          for (int sl = 0; sl < 2; sl++) {
            uint4 pw = *(const uint4*)&P[l31 * PSTR + sl*8 + hi*4];
            __builtin_memcpy(&pf[sl], &pw, 16);
          }
          __builtin_amdgcn_s_setprio(1);
#pragma unroll
          for (int sl = 0; sl < 2; sl++)
#pragma unroll
            for (int dt = 0; dt < 2; dt++)
              oa[dt] = mfma32(vf[sl][dt], pf[sl], oa[dt]);
          __builtin_amdgcn_s_setprio(0);
          __builtin_amdgcn_sched_barrier(0);
        }
      }
    }

    __builtin_amdgcn_s_barrier();
    __builtin_amdgcn_sched_barrier(0);
    if (t + 2 < nst) STAGE(cur, kv0 + 256);   // overwrite freed buffer
    cur ^= 1;
  }

  const int b = head >> 4, h = head & 15;
  {
    const float invl = 1.0f / pair_sum(lb);
    const size_t rowb = (size_t)(b * T_ + q0b + l31) * C_ + h * 64;
#pragma unroll
    for (int dt = 0; dt < 2; dt++)
#pragma unroll
      for (int rg = 0; rg < 4; rg++) {
        const int d0 = dt*32 + 8*rg + 4*hi;
        ushort4 ov;
        ov.x = f2bf(ob[dt][rg*4+0] * invl);
        ov.y = f2bf(ob[dt][rg*4+1] * invl);
        ov.z = f2bf(ob[dt][rg*4+2] * invl);
        ov.w = f2bf(ob[dt][rg*4+3] * invl);
        *(ushort4*)&AO[rowb + d0] = ov;
      }
  }
  {
    const float invl = 1.0f / pair_sum(la);
    const size_t rowb = (size_t)(b * T_ + q0a + l31) * C_ + h * 64;
#pragma unroll
    for (int dt = 0; dt < 2; dt++)
#pragma unroll
      for (int rg = 0; rg < 4; rg++) {
        const int d0 = dt*32 + 8*rg + 4*hi;
        ushort4 ov;
        ov.x = f2bf(oa[dt][rg*4+0] * invl);
        ov.y = f2bf(oa[dt][rg*4+1] * invl);
        ov.z = f2bf(oa[dt][rg*4+2] * invl);
        ov.w = f2bf(oa[dt][rg*4+3] * invl);
        *(ushort4*)&AO[rowb + d0] = ov;
      }
  }
}

extern "C" void kernel_launch(void* const* d_in, const int* in_sizes, int n_in,
                              void* d_out, int out_size, void* d_ws, size_t ws_size,
                              hipStream_t stream) {
  const float* x     = (const float*)d_in[0];
  const float* w_qkv = (const float*)d_in[1];
  const float* b_qkv = (const float*)d_in[2];
  const float* w_out = (const float*)d_in[3];
  const float* b_out = (const float*)d_in[4];
  float* out = (float*)d_out;

  ushort* xb    = (ushort*)d_ws;                    // 8192*1024
  ushort* wqkvb = xb    + (size_t)M_ * C_;          // 3072*1024
  ushort* woutb = wqkvb + (size_t)3 * C_ * C_;      // 1024*1024
  ushort* q     = woutb + (size_t)C_ * C_;          // [B,H,T,D] (exp2-domain scaled)
  ushort* kk    = q     + (size_t)M_ * C_;          // [B,H,T,D]
  ushort* vt    = kk    + (size_t)M_ * C_;          // [B,H,D,T]
  ushort* ao    = xb;                               // reuse xb (free after QKV GEMM)

  cvt3<<<2048, 256, 0, stream>>>(x, w_qkv, w_out, xb, wqkvb, woutb,
                                 (M_ * C_) / 4, (3 * C_ * C_) / 4, (C_ * C_) / 4);

  gemm_bt<0><<<dim3(3 * C_ / 128, M_ / 128), 256, 0, stream>>>(
      xb, wqkvb, b_qkv, C_, q, kk, vt, nullptr);

  // 4 waves x (32 low + 32 high) rows = 256 rows per block -> 512 blocks.
  attn_k<<<B_ * H_ * T_ / 256, 256, 0, stream>>>(q, kk, vt, ao);

  gemm_bt<1><<<dim3(C_ / 128, M_ / 128), 256, 0, stream>>>(
      ao, woutb, b_out, C_, nullptr, nullptr, nullptr, out);
}